// Round 10
// baseline (309.092 us; speedup 1.0000x reference)
//
#include <hip/hip_runtime.h>

typedef unsigned short u16;
typedef unsigned int u32;

typedef __attribute__((ext_vector_type(8))) short short8;
typedef __attribute__((ext_vector_type(4))) float floatx4;

__device__ __forceinline__ float bf2f(u16 u) { return __uint_as_float(((u32)u) << 16); }
__device__ __forceinline__ u16 f2bf(float f) {
    u32 x = __float_as_uint(f);
    x += 0x7fffu + ((x >> 16) & 1u);
    return (u16)(x >> 16);
}
__device__ __forceinline__ void gl_lds16(const void* g, void* l) {
    __builtin_amdgcn_global_load_lds((const __attribute__((address_space(1))) u32*)g,
                                     (__attribute__((address_space(3))) u32*)l, 16, 0, 0);
}

// Fragment-tiled ("swiz") layouts: data grouped in 1024B chunks of [16 rows x 32 k],
// element order = gl_lds16 lane order: u16 off = chunk*512 + (((k>>3)&3)*16 + (row&15))*8 + (k&7).
// A-operands (t, o): chunk = (row>>4)*24 + (k>>5)   [K=768 -> 24 kchunks]
// W-operands (qkv_w, proj_w): same with row=n.
// K-swiz (per bh, n x dh): chunk = (n>>4)*6 + (dh>>5)
// V-swiz (per bh): chunk = (n>>5)*12 + (dh>>4), lane = ((n>>3)&3)*16 + (dh&15), low3 = n&7

// ---------------- Kernel 1: x (B,C,D,H,W) -> t swiz bf16, + pos ----------------
__global__ __launch_bounds__(256) void k_tpos(const float* __restrict__ x,
                                              const float* __restrict__ pos,
                                              u16* __restrict__ t) {
    __shared__ float tile[64][65];
    const int b = blockIdx.z, hw0 = blockIdx.y * 64, cd0 = blockIdx.x * 64;
    const int tid = threadIdx.x;
#pragma unroll
    for (int i = 0; i < 16; i++) {
        int f = i * 256 + tid;
        int cdl = f >> 6, hwl = f & 63;
        int cd = cd0 + cdl, c = cd >> 3, d = cd & 7;
        tile[cdl][hwl] = x[(size_t)(((b * 96 + c) * 8 + d)) * 1024 + hw0 + hwl];
    }
    __syncthreads();
#pragma unroll
    for (int it = 0; it < 2; it++) {
        int u = it * 256 + tid;       // 512 units of 16B
        int ch = u >> 6, l = u & 63;
        int n16l = ch >> 1, kcl = ch & 1;
        int hwl = n16l * 16 + (l & 15);
        int cdl = kcl * 32 + (l >> 4) * 8;
        int row = b * 1024 + hw0 + hwl;
        int cd = cd0 + cdl;
        const float* pp = pos + (size_t)(hw0 + hwl) * 768 + cd;
        float4 p0 = *(const float4*)pp;
        float4 p1 = *(const float4*)(pp + 4);
        short8 v;
        v[0] = (short)f2bf(tile[cdl + 0][hwl] + p0.x);
        v[1] = (short)f2bf(tile[cdl + 1][hwl] + p0.y);
        v[2] = (short)f2bf(tile[cdl + 2][hwl] + p0.z);
        v[3] = (short)f2bf(tile[cdl + 3][hwl] + p0.w);
        v[4] = (short)f2bf(tile[cdl + 4][hwl] + p1.x);
        v[5] = (short)f2bf(tile[cdl + 5][hwl] + p1.y);
        v[6] = (short)f2bf(tile[cdl + 6][hwl] + p1.z);
        v[7] = (short)f2bf(tile[cdl + 7][hwl] + p1.w);
        size_t chunk = (size_t)(row >> 4) * 24 + (cd >> 5);
        *(short8*)(t + chunk * 512 + l * 8) = v;
    }
}

// ---------------- weight cvt: qkv_w swiz, proj_w swiz, pw_w row-major ----------------
__global__ __launch_bounds__(256) void k_cvt(const float* __restrict__ wq,
                                             const float* __restrict__ wp,
                                             const float* __restrict__ wpw,
                                             u16* __restrict__ out) {
    const int NQ = 144 * 24 * 64;          // qkv 16B-units
    const int NP = NQ + 48 * 24 * 64;      // + proj 16B-units
    int u = blockIdx.x * 256 + threadIdx.x;
    if (u < NP) {
        const float* w = (u < NQ) ? wq : wp;
        int ub = (u < NQ) ? u : u - NQ;
        int chunk = ub >> 6, l = ub & 63;
        int n16 = chunk / 24, kc = chunk - n16 * 24;
        int n = n16 * 16 + (l & 15);
        int k0 = kc * 32 + (l >> 4) * 8;
        const float* src = w + (size_t)n * 768 + k0;
        float4 a = *(const float4*)src;
        float4 b2 = *(const float4*)(src + 4);
        short8 v;
        v[0] = (short)f2bf(a.x);  v[1] = (short)f2bf(a.y);
        v[2] = (short)f2bf(a.z);  v[3] = (short)f2bf(a.w);
        v[4] = (short)f2bf(b2.x); v[5] = (short)f2bf(b2.y);
        v[6] = (short)f2bf(b2.z); v[7] = (short)f2bf(b2.w);
        *(short8*)(out + (size_t)u * 8) = v;
    } else {
        int i = u - NP;  // 9216 pw elements
        out[(size_t)NP * 8 + i] = f2bf(wpw[i]);
    }
}

// ---------------- GEMM: C(M,N) = A_swiz(M,K) * W_swiz(N,K)^T, bf16 MFMA ----------------
// BK=64, XCD-pinned swizzle. MODE 0 k/v epilogue staged through LDS -> 1024B coalesced stores.
// Fused stats: MODE 0 accumulates column sum-of-squares (q,k) into sqa/ska;
// MODE 1 accumulates row sum / sum-of-squares into musum/sqsum.
template <int MODE>
__global__ __launch_bounds__(256) void gemm_bt(const u16* __restrict__ A,
                                               const u16* __restrict__ Bw,
                                               int M, int N, int K,
                                               u16* __restrict__ qo, u16* __restrict__ ko,
                                               u16* __restrict__ vo,
                                               const float* __restrict__ bias,
                                               float* __restrict__ Co,
                                               float* __restrict__ sqa,
                                               float* __restrict__ ska,
                                               float* __restrict__ musum,
                                               float* __restrict__ sqsum) {
    __shared__ __align__(16) u16 lAB[32 * 512];  // 32KB: lA = [0..16), lB = [16..32) chunks
    u16* lA = lAB;
    u16* lB = lAB + 16 * 512;
    const int tid = threadIdx.x;
    const int lane = tid & 63;
    const int wv = tid >> 6;
    const int wr = wv >> 1, wc = wv & 1;
    const int ntiles = N >> 7;
    const int mtiles = M >> 7;                 // 64
    const int lin = blockIdx.x;
    const int xcd = lin & 7;
    const int idx = lin >> 3;
    const int mlocal = idx / ntiles;
    const int ntile = idx - mlocal * ntiles;
    const int m0 = (xcd * (mtiles >> 3) + mlocal) << 7;
    const int n0 = ntile << 7;
    const int lr = lane & 15;
    const int lq = lane >> 4;

    floatx4 acc[4][4];
#pragma unroll
    for (int i = 0; i < 4; i++)
#pragma unroll
        for (int j = 0; j < 4; j++) acc[i][j] = (floatx4){0.f, 0.f, 0.f, 0.f};

    const int m16 = m0 >> 4, n16 = n0 >> 4;
    for (int kc2 = 0; kc2 < (K >> 6); kc2++) {
        __syncthreads();
#pragma unroll
        for (int kh = 0; kh < 2; kh++) {
#pragma unroll
            for (int i = 0; i < 2; i++) {
                int ch16 = i * 4 + wv;       // 16-row block of the 128-row tile
                int kc = kc2 * 2 + kh;
                const u16* ga = A + ((size_t)(m16 + ch16) * 24 + kc) * 512 + lane * 8;
                gl_lds16(ga, (char*)lA + (kh * 8 + ch16) * 1024);
                const u16* gb = Bw + ((size_t)(n16 + ch16) * 24 + kc) * 512 + lane * 8;
                gl_lds16(gb, (char*)lB + (kh * 8 + ch16) * 1024);
            }
        }
        __syncthreads();
#pragma unroll
        for (int kh = 0; kh < 2; kh++) {
            short8 af[4], bfr[4];
#pragma unroll
            for (int tt = 0; tt < 4; tt++) {
                af[tt] = *(const short8*)(lA + ((kh * 8 + wr * 4 + tt) * 64 + lane) * 8);
                bfr[tt] = *(const short8*)(lB + ((kh * 8 + wc * 4 + tt) * 64 + lane) * 8);
            }
#pragma unroll
            for (int mt = 0; mt < 4; mt++)
#pragma unroll
                for (int nt = 0; nt < 4; nt++)
                    acc[mt][nt] = __builtin_amdgcn_mfma_f32_16x16x32_bf16(af[mt], bfr[nt], acc[mt][nt], 0, 0, 0);
        }
    }

    if (MODE == 0) {
        const int region = n0 / 768;       // whole block is q, k, or v
        const int n0r = n0 - region * 768;
        const int bb0 = m0 >> 10;
        // fused column sum-of-squares for q (region 0) and k (region 1)
        if (region < 2) {
            float* dst = (region == 0) ? sqa : ska;
#pragma unroll
            for (int nt = 0; nt < 4; nt++) {
                int colb = n0r + wc * 64 + nt * 16;
                int h = colb / 192;
                int dh = colb - h * 192 + lr;
                float s = 0.f;
#pragma unroll
                for (int mt = 0; mt < 4; mt++)
#pragma unroll
                    for (int r = 0; r < 4; r++) s += acc[mt][nt][r] * acc[mt][nt][r];
                s += __shfl_xor(s, 16);
                s += __shfl_xor(s, 32);
                if (lq == 0) atomicAdd(&dst[(bb0 * 4 + h) * 192 + dh], s);
            }
        }
        if (region == 0) {
            // q: direct row-major stores (32B segments)
#pragma unroll
            for (int nt = 0; nt < 4; nt++) {
                int colb = n0r + wc * 64 + nt * 16;
                int h = colb / 192;
                int dh = colb - h * 192 + lr;
#pragma unroll
                for (int mt = 0; mt < 4; mt++) {
#pragma unroll
                    for (int r = 0; r < 4; r++) {
                        int row = m0 + wr * 64 + mt * 16 + lq * 4 + r;
                        int b = row >> 10, n = row & 1023;
                        qo[((size_t)(b * 4 + h) * 1024 + n) * 192 + dh] = f2bf(acc[mt][nt][r]);
                    }
                }
            }
        } else {
            // k/v: stage the 128x128 bf16 tile in LDS at swiz-exact offsets, bulk-copy out
            __syncthreads();
            if (region == 1) {
#pragma unroll
                for (int nt = 0; nt < 4; nt++) {
                    int lch = wc * 2 + (nt >> 1);
                    int offbase = (((nt & 1) * 2 + (lr >> 3)) * 16) * 8 + (lr & 7);
#pragma unroll
                    for (int mt = 0; mt < 4; mt++) {
                        u16* cp2 = lAB + (((wr * 4 + mt) * 4 + lch) * 512);
#pragma unroll
                        for (int r = 0; r < 4; r++)
                            cp2[offbase + (lq * 4 + r) * 8] = f2bf(acc[mt][nt][r]);
                    }
                }
            } else {
#pragma unroll
                for (int nt = 0; nt < 4; nt++) {
#pragma unroll
                    for (int mt = 0; mt < 4; mt++) {
                        u16* cp2 = lAB + (((wr * 2 + (mt >> 1)) * 8 + wc * 4 + nt) * 512);
                        int ob = (((mt & 1) * 2 + (lq >> 1)) * 16 + lr) * 8 + (lq & 1) * 4;
#pragma unroll
                        for (int r = 0; r < 4; r++)
                            cp2[ob + r] = f2bf(acc[mt][nt][r]);
                    }
                }
            }
            __syncthreads();
            const int b = m0 >> 10;
            const int ml = m0 & 1023;
#pragma unroll
            for (int i = 0; i < 8; i++) {
                int ci = wv * 8 + i;
                short8 val = *(const short8*)(lAB + ci * 512 + lane * 8);
                if (region == 1) {
                    int a = ci >> 2, bb = ci & 3;
                    int cg = n0r + bb * 32;
                    int h = cg / 192;
                    int dh32 = (cg - h * 192) >> 5;
                    size_t gaddr = (size_t)(b * 4 + h) * 196608 +
                                   (size_t)((((ml >> 4) + a) * 6 + dh32)) * 512 + lane * 8;
                    *(short8*)(ko + gaddr) = val;
                } else {
                    int a = ci >> 3, bb = ci & 7;
                    int cg = n0r + bb * 16;
                    int h = cg / 192;
                    int dh16 = (cg - h * 192) >> 4;
                    size_t gaddr = (size_t)(b * 4 + h) * 196608 +
                                   (size_t)((((ml >> 5) + a) * 12 + dh16)) * 512 + lane * 8;
                    *(short8*)(vo + gaddr) = val;
                }
            }
        }
    } else {
        float bvv[4];
#pragma unroll
        for (int nt = 0; nt < 4; nt++) bvv[nt] = bias[n0 + wc * 64 + nt * 16 + lr];
#pragma unroll
        for (int nt = 0; nt < 4; nt++) {
            int col = n0 + wc * 64 + nt * 16 + lr;
#pragma unroll
            for (int mt = 0; mt < 4; mt++) {
#pragma unroll
                for (int r = 0; r < 4; r++) {
                    int row = m0 + wr * 64 + mt * 16 + lq * 4 + r;
                    Co[(size_t)row * N + col] = acc[mt][nt][r] + bvv[nt];
                }
            }
        }
        // fused LN row stats: sum and sum-of-squares over this block's 128 cols
#pragma unroll
        for (int mt = 0; mt < 4; mt++) {
#pragma unroll
            for (int r = 0; r < 4; r++) {
                float s = 0.f, ss = 0.f;
#pragma unroll
                for (int nt = 0; nt < 4; nt++) {
                    float v = acc[mt][nt][r] + bvv[nt];
                    s += v;
                    ss += v * v;
                }
#pragma unroll
                for (int m = 1; m < 16; m <<= 1) {
                    s += __shfl_xor(s, m);
                    ss += __shfl_xor(ss, m);
                }
                if (lr == 0) {
                    int row = m0 + wr * 64 + mt * 16 + lq * 4 + r;
                    atomicAdd(&musum[row], s);
                    atomicAdd(&sqsum[row], ss);
                }
            }
        }
    }
}

__global__ void k_scale(const float* __restrict__ sqq, const float* __restrict__ sqk,
                        const float* __restrict__ temp, float* __restrict__ cs) {
    int bh = blockIdx.x;
    int dh = threadIdx.x;
    float rq = 1.f / fmaxf(sqrtf(sqq[bh * 192 + dh]), 1e-12f);
    float rk = 1.f / fmaxf(sqrtf(sqk[bh * 192 + dh]), 1e-12f);
    cs[bh * 192 + dh] = rq * rk * temp[bh & 3];
}

// ---------------- LN stats finalize: sums -> mu, rstd ----------------
__global__ __launch_bounds__(256) void k_lnfin(const float* __restrict__ musum,
                                               const float* __restrict__ sqsum,
                                               float* __restrict__ mu,
                                               float* __restrict__ rstd) {
    int row = blockIdx.x * 256 + threadIdx.x;
    float m_ = musum[row] * (1.f / 768.f);
    float v = sqsum[row] * (1.f / 768.f) - m_ * m_;
    v = fmaxf(v, 0.f);
    mu[row] = m_;
    rstd[row] = rsqrtf(v + 1e-5f);
}

// ---------------- flash attention, dh-split: 1024 blocks (qb x bh x dh-half), 2 waves -------
// Each block: full QK^T + softmax (duplicated across halves), PV for its 96 dh cols.
// LDS 36KB (lP overlaid on lK[16..24) after a barrier) -> 4 blocks/CU = 2 waves/SIMD.
__global__ __launch_bounds__(128) void k_attn(const u16* __restrict__ q,
                                              const u16* __restrict__ kmat,
                                              const u16* __restrict__ vT,
                                              const float* __restrict__ cs,
                                              u16* __restrict__ o) {
    __shared__ __align__(16) u16 lK[24 * 512];  // 24KB; last 8KB doubles as lP
    __shared__ __align__(16) u16 lV[12 * 512];  // 12KB (this block's dh-half of V)
    const int lin = blockIdx.x;
    const int xcd = lin & 7;
    const int rest = lin >> 3;
    const int qb = rest & 15;
    const int hh = (rest >> 4) & 1;   // dh half
    const int bh = xcd * 4 + (rest >> 5);
    const int b = bh >> 2, h = bh & 3;
    const int tid = threadIdx.x;
    const int lane = tid & 63;
    const int wv = tid >> 6;   // 0..1
    const int lr = lane & 15;
    const int lq = lane >> 4;
    const int koff = lq * 8;

    const u16* qbase = q + (size_t)bh * 1024 * 192;
    const u16* kbase = kmat + (size_t)bh * 196608;
    const u16* vbase = vT + (size_t)bh * 196608;
    const float* cp = cs + bh * 192;

    // Q fragments for the wave's 2 row-tiles, pre-scaled
    short8 qf[2][6];
#pragma unroll
    for (int t = 0; t < 2; t++) {
        const int qrow = qb * 64 + wv * 32 + t * 16 + lr;
        const u16* qp = qbase + (size_t)qrow * 192;
#pragma unroll
        for (int ks = 0; ks < 6; ks++) {
            short8 raw = *(const short8*)(qp + ks * 32 + koff);
            short8 sc;
#pragma unroll
            for (int j = 0; j < 8; j++) {
                float f = bf2f((u16)raw[j]) * cp[ks * 32 + koff + j];
                sc[j] = (short)f2bf(f);
            }
            qf[t][ks] = sc;
        }
    }

    float l_r[2][4];
    floatx4 oacc[2][6];
#pragma unroll
    for (int t = 0; t < 2; t++) {
#pragma unroll
        for (int r = 0; r < 4; r++) l_r[t][r] = 0.f;
#pragma unroll
        for (int vt = 0; vt < 6; vt++) oacc[t][vt] = (floatx4){0.f, 0.f, 0.f, 0.f};
    }

    u16* lp = lK + 16 * 512 + wv * 2048;  // overlay: per-wave 2 P-tiles in lK[16..24)

    for (int kb = 0; kb < 16; kb++) {
        __syncthreads();  // prior QK/PV/P reads done -> safe to restage
        // stage 24 K chunks + 12 V chunks (this dh-half) with 2 waves
#pragma unroll
        for (int i = 0; i < 12; i++) {
            int ch = i * 2 + wv;  // 0..23
            int ks = ch >> 2, nt = ch & 3;
            const u16* gk = kbase + ((size_t)(kb * 4 + nt) * 6 + ks) * 512 + lane * 8;
            gl_lds16(gk, (char*)lK + ch * 1024);
        }
#pragma unroll
        for (int i = 0; i < 6; i++) {
            int lch = i * 2 + wv;  // 0..11
            int ks2 = lch / 6, vt2 = lch - ks2 * 6;
            const u16* gv = vbase + ((size_t)(kb * 2 + ks2) * 12 + hh * 6 + vt2) * 512 + lane * 8;
            gl_lds16(gv, (char*)lV + lch * 1024);
        }
        __syncthreads();

        // S = Qs * K^T for both row-tiles; each kf read feeds 2 MFMAs
        floatx4 s0[4], s1[4];
#pragma unroll
        for (int nt = 0; nt < 4; nt++) {
            s0[nt] = (floatx4){0.f, 0.f, 0.f, 0.f};
            s1[nt] = (floatx4){0.f, 0.f, 0.f, 0.f};
        }
#pragma unroll
        for (int ks = 0; ks < 6; ks++) {
#pragma unroll
            for (int nt = 0; nt < 4; nt++) {
                short8 kf = *(const short8*)(lK + ((ks * 4 + nt) * 64 + lane) * 8);
                s0[nt] = __builtin_amdgcn_mfma_f32_16x16x32_bf16(qf[0][ks], kf, s0[nt], 0, 0, 0);
                s1[nt] = __builtin_amdgcn_mfma_f32_16x16x32_bf16(qf[1][ks], kf, s1[nt], 0, 0, 0);
            }
        }

        // exp (no max shift) + row-sum, both tiles
        float rs0[4] = {0.f, 0.f, 0.f, 0.f}, rs1[4] = {0.f, 0.f, 0.f, 0.f};
#pragma unroll
        for (int nt = 0; nt < 4; nt++)
#pragma unroll
            for (int r = 0; r < 4; r++) {
                float p0 = __expf(s0[nt][r]);
                s0[nt][r] = p0;
                rs0[r] += p0;
                float p1 = __expf(s1[nt][r]);
                s1[nt][r] = p1;
                rs1[r] += p1;
            }
#pragma unroll
        for (int m = 1; m < 16; m <<= 1)
#pragma unroll
            for (int r = 0; r < 4; r++) {
                rs0[r] += __shfl_xor(rs0[r], m);
                rs1[r] += __shfl_xor(rs1[r], m);
            }
#pragma unroll
        for (int r = 0; r < 4; r++) {
            l_r[0][r] += rs0[r];
            l_r[1][r] += rs1[r];
        }

        __syncthreads();  // both waves done reading lK before lP overlay writes
#pragma unroll
        for (int nt = 0; nt < 4; nt++) {
            int base2 = (nt >> 1) * 512 + ((nt & 1) * 2 + (lr >> 3)) * 128 + (lr & 7);
#pragma unroll
            for (int r = 0; r < 4; r++) {
                lp[base2 + (lq * 4 + r) * 8] = f2bf(s0[nt][r]);
                lp[1024 + base2 + (lq * 4 + r) * 8] = f2bf(s1[nt][r]);
            }
        }

        // O += P * V (this dh-half); each vf read feeds 2 MFMAs
#pragma unroll
        for (int ks2 = 0; ks2 < 2; ks2++) {
            short8 pf0 = *(const short8*)(lp + ks2 * 512 + lane * 8);
            short8 pf1 = *(const short8*)(lp + 1024 + ks2 * 512 + lane * 8);
#pragma unroll
            for (int vt = 0; vt < 6; vt++) {
                short8 vf = *(const short8*)(lV + ((ks2 * 6 + vt) * 64 + lane) * 8);
                oacc[0][vt] = __builtin_amdgcn_mfma_f32_16x16x32_bf16(pf0, vf, oacc[0][vt], 0, 0, 0);
                oacc[1][vt] = __builtin_amdgcn_mfma_f32_16x16x32_bf16(pf1, vf, oacc[1][vt], 0, 0, 0);
            }
        }
    }

    // epilogue: divide by l, write o (this dh-half) in swiz (A-operand) layout
#pragma unroll
    for (int t = 0; t < 2; t++) {
        float inv[4];
#pragma unroll
        for (int r = 0; r < 4; r++) inv[r] = 1.f / l_r[t][r];
#pragma unroll
        for (int vt = 0; vt < 6; vt++) {
            int col = h * 192 + hh * 96 + vt * 16 + lr;
#pragma unroll
            for (int r = 0; r < 4; r++) {
                int rowg = b * 1024 + qb * 64 + wv * 32 + t * 16 + lq * 4 + r;
                size_t addr = (size_t)(rowg >> 4) * 12288 + (col >> 5) * 512 +
                              ((col >> 3) & 3) * 128 + (rowg & 15) * 8 + (col & 7);
                o[addr] = f2bf(oacc[t][vt][r] * inv[r]);
            }
        }
    }
}

// ---------------- LN apply + transpose back + residual: y = LN(o2)^T + x ----------------
__global__ __launch_bounds__(256) void k_lnt(const float* __restrict__ o2,
                                             const float* __restrict__ mu,
                                             const float* __restrict__ rstd,
                                             const float* __restrict__ gamma,
                                             const float* __restrict__ beta,
                                             const float* __restrict__ x,
                                             float* __restrict__ y) {
    __shared__ float tile[64][65];
    const int b = blockIdx.z, hw0 = blockIdx.y * 64, cd0 = blockIdx.x * 64;
    const int tid = threadIdx.x;
#pragma unroll
    for (int i = 0; i < 16; i++) {
        int f = i * 256 + tid;
        int hwl = f >> 6, cdl = f & 63;
        int row = b * 1024 + hw0 + hwl;
        float v = o2[(size_t)row * 768 + cd0 + cdl];
        v = (v - mu[row]) * rstd[row] * gamma[cd0 + cdl] + beta[cd0 + cdl];
        tile[hwl][cdl] = v;
    }
    __syncthreads();
#pragma unroll
    for (int i = 0; i < 16; i++) {
        int f = i * 256 + tid;
        int cdl = f >> 6, hwl = f & 63;
        int cd = cd0 + cdl, c = cd >> 3, d = cd & 7;
        size_t addr = (size_t)((b * 96 + c) * 8 + d) * 1024 + hw0 + hwl;
        y[addr] = tile[hwl][cdl] + x[addr];
    }
}

// ---------------- depthwise 3x3x3 conv: LDS-staged channel + rolling d-window ----------------
__global__ __launch_bounds__(256) void k_dw(const float* __restrict__ y,
                                            const float* __restrict__ w,
                                            const float* __restrict__ bias,
                                            float* __restrict__ z) {
    __shared__ float ly[8192];  // [d][h][w]
    const int bc = blockIdx.x;
    const int c = bc % 96;
    const int tid = threadIdx.x;
    const size_t base = (size_t)bc * 8192;

#pragma unroll
    for (int i = 0; i < 8; i++) {
        int i4 = i * 256 + tid;
        *(float4*)(ly + i4 * 4) = *(const float4*)(y + base + i4 * 4);
    }
    float wt[27];
#pragma unroll
    for (int j = 0; j < 27; j++) wt[j] = w[c * 27 + j];
    const float bv = bias[c];
    __syncthreads();

    const int wcol = tid & 31;
    const int hh = tid >> 5;  // 0..7

    for (int hb = 0; hb < 4; hb++) {
        const int h = hb * 8 + hh;
        float pl[3][9];
        auto loadplane = [&](int dd, float* p) {
#pragma unroll
            for (int kh = 0; kh < 3; kh++) {
                int h2 = h + kh - 1;
                bool hok = (unsigned)h2 < 32u;
                const float* row = ly + dd * 1024 + h2 * 32;
#pragma unroll
                for (int kw = 0; kw < 3; kw++) {
                    int w2 = wcol + kw - 1;
                    bool ok = hok && (unsigned)w2 < 32u;
                    p[kh * 3 + kw] = ok ? row[w2] : 0.f;
                }
            }
        };
#pragma unroll
        for (int j = 0; j < 9; j++) pl[0][j] = 0.f;  // d=-1 plane
        loadplane(0, pl[1]);
#pragma unroll
        for (int d = 0; d < 8; d++) {
            if (d < 7) loadplane(d + 1, pl[2]);
            else {
#pragma unroll
                for (int j = 0; j < 9; j++) pl[2][j] = 0.f;
            }
            float acc = bv;
#pragma unroll
            for (int kd = 0; kd < 3; kd++)
#pragma unroll
                for (int j = 0; j < 9; j++) acc += wt[kd * 9 + j] * pl[kd][j];
            z[base + d * 1024 + h * 32 + wcol] = acc;
#pragma unroll
            for (int j = 0; j < 9; j++) { pl[0][j] = pl[1][j]; pl[1][j] = pl[2][j]; }
        }
    }
}

// ---------------- pointwise conv via MFMA: out = y + pw_b + W(96x96) * Z(96 x pos) ----------------
__global__ __launch_bounds__(256) void k_pw(const float* __restrict__ z,
                                            const u16* __restrict__ wbf,   // bf16 96x96 row-major
                                            const float* __restrict__ bias,
                                            float* __restrict__ out) {
    __shared__ __align__(16) u16 lZ[128 * 104];
    __shared__ __align__(16) u16 lW[96 * 104];
    const int tid = threadIdx.x;
    const int lane = tid & 63;
    const int wv = tid >> 6;
    const int lr = lane & 15;
    const int lq = lane >> 4;
    const int koff = lq * 8;

    const int idx = blockIdx.x;
    const int q = idx & 7;
    const int bd = idx >> 3;
    const int b = bd >> 3, d = bd & 7;
    const int pos0 = q * 128;

    for (int i = tid; i < 96 * 96; i += 256) {
        int row = i / 96, col = i - row * 96;
        lW[row * 104 + col] = wbf[i];
    }
    {
        const int pos = tid & 127;
        const int cc0 = (tid >> 7) * 48;
        const size_t gbase = ((size_t)b * 96 * 8 + d) * 1024 + pos0 + pos;
#pragma unroll
        for (int g = 0; g < 6; g++) {
            short8 v;
#pragma unroll
            for (int j = 0; j < 8; j++) {
                int cc = cc0 + g * 8 + j;
                v[j] = (short)f2bf(z[gbase + (size_t)cc * 8192]);
            }
            *(short8*)(lZ + pos * 104 + cc0 + g * 8) = v;
        }
    }
    __syncthreads();

    floatx4 acc[6][2];
#pragma unroll
    for (int m = 0; m < 6; m++)
#pragma unroll
        for (int nt = 0; nt < 2; nt++) acc[m][nt] = (floatx4){0.f, 0.f, 0.f, 0.f};

#pragma unroll
    for (int ks = 0; ks < 3; ks++) {
        short8 bfrg[2];
#pragma unroll
        for (int nt = 0; nt < 2; nt++)
            bfrg[nt] = *(const short8*)(lZ + (wv * 32 + nt * 16 + lr) * 104 + ks * 32 + koff);
#pragma unroll
        for (int m = 0; m < 6; m++) {
            short8 afr = *(const short8*)(lW + (m * 16 + lr) * 104 + ks * 32 + koff);
#pragma unroll
            for (int nt = 0; nt < 2; nt++)
                acc[m][nt] = __builtin_amdgcn_mfma_f32_16x16x32_bf16(afr, bfrg[nt], acc[m][nt], 0, 0, 0);
        }
    }

#pragma unroll
    for (int m = 0; m < 6; m++) {
#pragma unroll
        for (int r = 0; r < 4; r++) {
            int c = m * 16 + lq * 4 + r;
            float bv = bias[c];
            size_t rowbase = ((size_t)(b * 96 + c) * 8 + d) * 1024 + pos0;
#pragma unroll
            for (int nt = 0; nt < 2; nt++) {
                int pos = wv * 32 + nt * 16 + lr;
                size_t a = rowbase + pos;
                out[a] = out[a] + bv + acc[m][nt][r];
            }
        }
    }
}

extern "C" void kernel_launch(void* const* d_in, const int* in_sizes, int n_in,
                              void* d_out, int out_size, void* d_ws, size_t ws_size,
                              hipStream_t stream) {
    (void)in_sizes; (void)n_in; (void)out_size; (void)ws_size;
    const float* x      = (const float*)d_in[0];
    const float* pos    = (const float*)d_in[1];
    const float* qkv_w  = (const float*)d_in[2];
    const float* proj_w = (const float*)d_in[3];
    const float* proj_b = (const float*)d_in[4];
    const float* temp   = (const float*)d_in[5];
    const float* ln_g   = (const float*)d_in[6];
    const float* ln_b   = (const float*)d_in[7];
    const float* dw_w   = (const float*)d_in[8];
    const float* dw_b   = (const float*)d_in[9];
    const float* pw_w   = (const float*)d_in[10];
    const float* pw_b   = (const float*)d_in[11];
    float* out = (float*)d_out;
    char* ws = (char*)d_ws;

    u16* t    = (u16*)(ws + 0);           // swiz A, 12.58MB ; later aliased by o (swiz) and z
    u16* vT   = (u16*)(ws + 12582912);    // v swiz, 12.58MB
    u16* q    = (u16*)(ws + 25165824);    // row-major, 12.58MB ; later o2 (with kk)
    u16* kk   = (u16*)(ws + 37748736);    // k swiz, 12.58MB
    u16* wqb  = (u16*)(ws + 50331648);    // qkv_w swiz + proj_w swiz + pw_w, ~4.74MB
    float* cs    = (float*)(ws + 55150592);
    float* sqq   = (float*)(ws + 55175168);
    float* sqk   = (float*)(ws + 55199744);
    float* musum = (float*)(ws + 55224320);
    float* sqsum = (float*)(ws + 55257088);
    float* mu    = (float*)(ws + 55289856);
    float* rstd  = (float*)(ws + 55322624);
    u16* wpb  = wqb + 2304 * 768;
    u16* wpwb = wqb + 2304 * 768 + 768 * 768;
    u16* o   = t;
    float* o2 = (float*)q;
    float* z  = (float*)t;
    float* y  = out;

    k_tpos<<<dim3(12, 16, 8), 256, 0, stream>>>(x, pos, t);
    k_cvt<<<1188, 256, 0, stream>>>(qkv_w, proj_w, pw_w, wqb);
    hipMemsetAsync(sqq, 0, 114688, stream);  // sqq + sqk + musum + sqsum
    gemm_bt<0><<<1152, 256, 0, stream>>>(t, wqb, 8192, 2304, 768, q, kk, vT, nullptr, nullptr,
                                         sqq, sqk, nullptr, nullptr);
    k_scale<<<32, 192, 0, stream>>>(sqq, sqk, temp, cs);
    k_attn<<<1024, 128, 0, stream>>>(q, kk, vT, cs, o);
    gemm_bt<1><<<384, 256, 0, stream>>>(o, wpb, 8192, 768, 768, nullptr, nullptr, nullptr, proj_b,
                                        o2, nullptr, nullptr, musum, sqsum);
    k_lnfin<<<32, 256, 0, stream>>>(musum, sqsum, mu, rstd);
    k_lnt<<<dim3(12, 16, 8), 256, 0, stream>>>(o2, mu, rstd, ln_g, ln_b, x, y);
    k_dw<<<768, 256, 0, stream>>>(y, dw_w, dw_b, z);
    k_pw<<<512, 256, 0, stream>>>(z, wpwb, pw_b, out);
}

// Round 11
// 287.184 us; speedup vs baseline: 1.0763x; 1.0763x over previous
//
#include <hip/hip_runtime.h>

typedef unsigned short u16;
typedef unsigned int u32;

typedef __attribute__((ext_vector_type(8))) short short8;
typedef __attribute__((ext_vector_type(4))) float floatx4;

__device__ __forceinline__ float bf2f(u16 u) { return __uint_as_float(((u32)u) << 16); }
__device__ __forceinline__ u16 f2bf(float f) {
    u32 x = __float_as_uint(f);
    x += 0x7fffu + ((x >> 16) & 1u);
    return (u16)(x >> 16);
}
__device__ __forceinline__ void gl_lds16(const void* g, void* l) {
    __builtin_amdgcn_global_load_lds((const __attribute__((address_space(1))) u32*)g,
                                     (__attribute__((address_space(3))) u32*)l, 16, 0, 0);
}

// Fragment-tiled ("swiz") layouts: data grouped in 1024B chunks of [16 rows x 32 k],
// element order = gl_lds16 lane order: u16 off = chunk*512 + (((k>>3)&3)*16 + (row&15))*8 + (k&7).
// A-operands (t, o): chunk = (row>>4)*24 + (k>>5)   [K=768 -> 24 kchunks]
// W-operands (qkv_w, proj_w): same with row=n.
// K-swiz (per bh, n x dh): chunk = (n>>4)*6 + (dh>>5)
// V-swiz (per bh): chunk = (n>>5)*12 + (dh>>4), lane = ((n>>3)&3)*16 + (dh&15), low3 = n&7

// ---------------- Kernel 1: x (B,C,D,H,W) -> t swiz bf16, + pos ----------------
__global__ __launch_bounds__(256) void k_tpos(const float* __restrict__ x,
                                              const float* __restrict__ pos,
                                              u16* __restrict__ t) {
    __shared__ float tile[64][65];
    const int b = blockIdx.z, hw0 = blockIdx.y * 64, cd0 = blockIdx.x * 64;
    const int tid = threadIdx.x;
#pragma unroll
    for (int i = 0; i < 16; i++) {
        int f = i * 256 + tid;
        int cdl = f >> 6, hwl = f & 63;
        int cd = cd0 + cdl, c = cd >> 3, d = cd & 7;
        tile[cdl][hwl] = x[(size_t)(((b * 96 + c) * 8 + d)) * 1024 + hw0 + hwl];
    }
    __syncthreads();
#pragma unroll
    for (int it = 0; it < 2; it++) {
        int u = it * 256 + tid;       // 512 units of 16B
        int ch = u >> 6, l = u & 63;
        int n16l = ch >> 1, kcl = ch & 1;
        int hwl = n16l * 16 + (l & 15);
        int cdl = kcl * 32 + (l >> 4) * 8;
        int row = b * 1024 + hw0 + hwl;
        int cd = cd0 + cdl;
        const float* pp = pos + (size_t)(hw0 + hwl) * 768 + cd;
        float4 p0 = *(const float4*)pp;
        float4 p1 = *(const float4*)(pp + 4);
        short8 v;
        v[0] = (short)f2bf(tile[cdl + 0][hwl] + p0.x);
        v[1] = (short)f2bf(tile[cdl + 1][hwl] + p0.y);
        v[2] = (short)f2bf(tile[cdl + 2][hwl] + p0.z);
        v[3] = (short)f2bf(tile[cdl + 3][hwl] + p0.w);
        v[4] = (short)f2bf(tile[cdl + 4][hwl] + p1.x);
        v[5] = (short)f2bf(tile[cdl + 5][hwl] + p1.y);
        v[6] = (short)f2bf(tile[cdl + 6][hwl] + p1.z);
        v[7] = (short)f2bf(tile[cdl + 7][hwl] + p1.w);
        size_t chunk = (size_t)(row >> 4) * 24 + (cd >> 5);
        *(short8*)(t + chunk * 512 + l * 8) = v;
    }
}

// ---------------- weight cvt: qkv_w swiz, proj_w swiz, pw_w row-major ----------------
__global__ __launch_bounds__(256) void k_cvt(const float* __restrict__ wq,
                                             const float* __restrict__ wp,
                                             const float* __restrict__ wpw,
                                             u16* __restrict__ out) {
    const int NQ = 144 * 24 * 64;          // qkv 16B-units
    const int NP = NQ + 48 * 24 * 64;      // + proj 16B-units
    int u = blockIdx.x * 256 + threadIdx.x;
    if (u < NP) {
        const float* w = (u < NQ) ? wq : wp;
        int ub = (u < NQ) ? u : u - NQ;
        int chunk = ub >> 6, l = ub & 63;
        int n16 = chunk / 24, kc = chunk - n16 * 24;
        int n = n16 * 16 + (l & 15);
        int k0 = kc * 32 + (l >> 4) * 8;
        const float* src = w + (size_t)n * 768 + k0;
        float4 a = *(const float4*)src;
        float4 b2 = *(const float4*)(src + 4);
        short8 v;
        v[0] = (short)f2bf(a.x);  v[1] = (short)f2bf(a.y);
        v[2] = (short)f2bf(a.z);  v[3] = (short)f2bf(a.w);
        v[4] = (short)f2bf(b2.x); v[5] = (short)f2bf(b2.y);
        v[6] = (short)f2bf(b2.z); v[7] = (short)f2bf(b2.w);
        *(short8*)(out + (size_t)u * 8) = v;
    } else {
        int i = u - NP;  // 9216 pw elements
        out[(size_t)NP * 8 + i] = f2bf(wpw[i]);
    }
}

// ---------------- GEMM: C(M,N) = A_swiz(M,K) * W_swiz(N,K)^T, bf16 MFMA ----------------
// BK=64, XCD-pinned swizzle. MODE 0 k/v epilogue staged through LDS -> 1024B coalesced stores.
// Fused stats: MODE 0 accumulates column sum-of-squares (q,k) into sqa/ska;
// MODE 1 accumulates row sum / sum-of-squares into musum/sqsum.
template <int MODE>
__global__ __launch_bounds__(256) void gemm_bt(const u16* __restrict__ A,
                                               const u16* __restrict__ Bw,
                                               int M, int N, int K,
                                               u16* __restrict__ qo, u16* __restrict__ ko,
                                               u16* __restrict__ vo,
                                               const float* __restrict__ bias,
                                               float* __restrict__ Co,
                                               float* __restrict__ sqa,
                                               float* __restrict__ ska,
                                               float* __restrict__ musum,
                                               float* __restrict__ sqsum) {
    __shared__ __align__(16) u16 lAB[32 * 512];  // 32KB: lA = [0..16), lB = [16..32) chunks
    u16* lA = lAB;
    u16* lB = lAB + 16 * 512;
    const int tid = threadIdx.x;
    const int lane = tid & 63;
    const int wv = tid >> 6;
    const int wr = wv >> 1, wc = wv & 1;
    const int ntiles = N >> 7;
    const int mtiles = M >> 7;                 // 64
    const int lin = blockIdx.x;
    const int xcd = lin & 7;
    const int idx = lin >> 3;
    const int mlocal = idx / ntiles;
    const int ntile = idx - mlocal * ntiles;
    const int m0 = (xcd * (mtiles >> 3) + mlocal) << 7;
    const int n0 = ntile << 7;
    const int lr = lane & 15;
    const int lq = lane >> 4;

    floatx4 acc[4][4];
#pragma unroll
    for (int i = 0; i < 4; i++)
#pragma unroll
        for (int j = 0; j < 4; j++) acc[i][j] = (floatx4){0.f, 0.f, 0.f, 0.f};

    const int m16 = m0 >> 4, n16 = n0 >> 4;
    for (int kc2 = 0; kc2 < (K >> 6); kc2++) {
        __syncthreads();
#pragma unroll
        for (int kh = 0; kh < 2; kh++) {
#pragma unroll
            for (int i = 0; i < 2; i++) {
                int ch16 = i * 4 + wv;       // 16-row block of the 128-row tile
                int kc = kc2 * 2 + kh;
                const u16* ga = A + ((size_t)(m16 + ch16) * 24 + kc) * 512 + lane * 8;
                gl_lds16(ga, (char*)lA + (kh * 8 + ch16) * 1024);
                const u16* gb = Bw + ((size_t)(n16 + ch16) * 24 + kc) * 512 + lane * 8;
                gl_lds16(gb, (char*)lB + (kh * 8 + ch16) * 1024);
            }
        }
        __syncthreads();
#pragma unroll
        for (int kh = 0; kh < 2; kh++) {
            short8 af[4], bfr[4];
#pragma unroll
            for (int tt = 0; tt < 4; tt++) {
                af[tt] = *(const short8*)(lA + ((kh * 8 + wr * 4 + tt) * 64 + lane) * 8);
                bfr[tt] = *(const short8*)(lB + ((kh * 8 + wc * 4 + tt) * 64 + lane) * 8);
            }
#pragma unroll
            for (int mt = 0; mt < 4; mt++)
#pragma unroll
                for (int nt = 0; nt < 4; nt++)
                    acc[mt][nt] = __builtin_amdgcn_mfma_f32_16x16x32_bf16(af[mt], bfr[nt], acc[mt][nt], 0, 0, 0);
        }
    }

    if (MODE == 0) {
        const int region = n0 / 768;       // whole block is q, k, or v
        const int n0r = n0 - region * 768;
        const int bb0 = m0 >> 10;
        // fused column sum-of-squares for q (region 0) and k (region 1)
        if (region < 2) {
            float* dst = (region == 0) ? sqa : ska;
#pragma unroll
            for (int nt = 0; nt < 4; nt++) {
                int colb = n0r + wc * 64 + nt * 16;
                int h = colb / 192;
                int dh = colb - h * 192 + lr;
                float s = 0.f;
#pragma unroll
                for (int mt = 0; mt < 4; mt++)
#pragma unroll
                    for (int r = 0; r < 4; r++) s += acc[mt][nt][r] * acc[mt][nt][r];
                s += __shfl_xor(s, 16);
                s += __shfl_xor(s, 32);
                if (lq == 0) atomicAdd(&dst[(bb0 * 4 + h) * 192 + dh], s);
            }
        }
        if (region == 0) {
            // q: direct row-major stores (32B segments)
#pragma unroll
            for (int nt = 0; nt < 4; nt++) {
                int colb = n0r + wc * 64 + nt * 16;
                int h = colb / 192;
                int dh = colb - h * 192 + lr;
#pragma unroll
                for (int mt = 0; mt < 4; mt++) {
#pragma unroll
                    for (int r = 0; r < 4; r++) {
                        int row = m0 + wr * 64 + mt * 16 + lq * 4 + r;
                        int b = row >> 10, n = row & 1023;
                        qo[((size_t)(b * 4 + h) * 1024 + n) * 192 + dh] = f2bf(acc[mt][nt][r]);
                    }
                }
            }
        } else {
            // k/v: stage the 128x128 bf16 tile in LDS at swiz-exact offsets, bulk-copy out
            __syncthreads();
            if (region == 1) {
#pragma unroll
                for (int nt = 0; nt < 4; nt++) {
                    int lch = wc * 2 + (nt >> 1);
                    int offbase = (((nt & 1) * 2 + (lr >> 3)) * 16) * 8 + (lr & 7);
#pragma unroll
                    for (int mt = 0; mt < 4; mt++) {
                        u16* cp2 = lAB + (((wr * 4 + mt) * 4 + lch) * 512);
#pragma unroll
                        for (int r = 0; r < 4; r++)
                            cp2[offbase + (lq * 4 + r) * 8] = f2bf(acc[mt][nt][r]);
                    }
                }
            } else {
#pragma unroll
                for (int nt = 0; nt < 4; nt++) {
#pragma unroll
                    for (int mt = 0; mt < 4; mt++) {
                        u16* cp2 = lAB + (((wr * 2 + (mt >> 1)) * 8 + wc * 4 + nt) * 512);
                        int ob = (((mt & 1) * 2 + (lq >> 1)) * 16 + lr) * 8 + (lq & 1) * 4;
#pragma unroll
                        for (int r = 0; r < 4; r++)
                            cp2[ob + r] = f2bf(acc[mt][nt][r]);
                    }
                }
            }
            __syncthreads();
            const int b = m0 >> 10;
            const int ml = m0 & 1023;
#pragma unroll
            for (int i = 0; i < 8; i++) {
                int ci = wv * 8 + i;
                short8 val = *(const short8*)(lAB + ci * 512 + lane * 8);
                if (region == 1) {
                    int a = ci >> 2, bb = ci & 3;
                    int cg = n0r + bb * 32;
                    int h = cg / 192;
                    int dh32 = (cg - h * 192) >> 5;
                    size_t gaddr = (size_t)(b * 4 + h) * 196608 +
                                   (size_t)((((ml >> 4) + a) * 6 + dh32)) * 512 + lane * 8;
                    *(short8*)(ko + gaddr) = val;
                } else {
                    int a = ci >> 3, bb = ci & 7;
                    int cg = n0r + bb * 16;
                    int h = cg / 192;
                    int dh16 = (cg - h * 192) >> 4;
                    size_t gaddr = (size_t)(b * 4 + h) * 196608 +
                                   (size_t)((((ml >> 5) + a) * 12 + dh16)) * 512 + lane * 8;
                    *(short8*)(vo + gaddr) = val;
                }
            }
        }
    } else {
        float bvv[4];
#pragma unroll
        for (int nt = 0; nt < 4; nt++) bvv[nt] = bias[n0 + wc * 64 + nt * 16 + lr];
#pragma unroll
        for (int nt = 0; nt < 4; nt++) {
            int col = n0 + wc * 64 + nt * 16 + lr;
#pragma unroll
            for (int mt = 0; mt < 4; mt++) {
#pragma unroll
                for (int r = 0; r < 4; r++) {
                    int row = m0 + wr * 64 + mt * 16 + lq * 4 + r;
                    Co[(size_t)row * N + col] = acc[mt][nt][r] + bvv[nt];
                }
            }
        }
        // fused LN row stats: sum and sum-of-squares over this block's 128 cols
#pragma unroll
        for (int mt = 0; mt < 4; mt++) {
#pragma unroll
            for (int r = 0; r < 4; r++) {
                float s = 0.f, ss = 0.f;
#pragma unroll
                for (int nt = 0; nt < 4; nt++) {
                    float v = acc[mt][nt][r] + bvv[nt];
                    s += v;
                    ss += v * v;
                }
#pragma unroll
                for (int m = 1; m < 16; m <<= 1) {
                    s += __shfl_xor(s, m);
                    ss += __shfl_xor(ss, m);
                }
                if (lr == 0) {
                    int row = m0 + wr * 64 + mt * 16 + lq * 4 + r;
                    atomicAdd(&musum[row], s);
                    atomicAdd(&sqsum[row], ss);
                }
            }
        }
    }
}

// ---------------- flash attention: 2-wave blocks, 32 q-rows/wave (2 tiles), no-max softmax ----
// (round-9 structure; cs computed inline from sqq/sqk/temp, removing the k_scale launch)
__global__ __launch_bounds__(128) void k_attn(const u16* __restrict__ q,
                                              const u16* __restrict__ kmat,
                                              const u16* __restrict__ vT,
                                              const float* __restrict__ sqq,
                                              const float* __restrict__ sqk,
                                              const float* __restrict__ temp,
                                              u16* __restrict__ o) {
    __shared__ __align__(16) u16 lK[24 * 512];
    __shared__ __align__(16) u16 lV[24 * 512];
    __shared__ __align__(16) u16 lP[2 * 2048];  // per-wave 2 P-tiles
    const int lin = blockIdx.x;
    const int qb = (lin >> 3) & 15;
    const int bh = (lin & 7) * 4 + (lin >> 7);
    const int b = bh >> 2, h = bh & 3;
    const int tid = threadIdx.x;
    const int lane = tid & 63;
    const int wv = tid >> 6;   // 0..1
    const int lr = lane & 15;
    const int lq = lane >> 4;
    const int koff = lq * 8;

    const u16* qbase = q + (size_t)bh * 1024 * 192;
    const u16* kbase = kmat + (size_t)bh * 196608;
    const u16* vbase = vT + (size_t)bh * 196608;
    const float* sqp = sqq + bh * 192;
    const float* skp = sqk + bh * 192;
    const float tempv = temp[h];

    // Q fragments for the wave's 2 row-tiles, pre-scaled by rq*rk*temp (== old cs)
    short8 qf[2][6];
#pragma unroll
    for (int ks = 0; ks < 6; ks++) {
        float scf[8];
#pragma unroll
        for (int j = 0; j < 8; j++) {
            int dh = ks * 32 + koff + j;
            float rq = 1.f / fmaxf(sqrtf(sqp[dh]), 1e-12f);
            float rk = 1.f / fmaxf(sqrtf(skp[dh]), 1e-12f);
            scf[j] = rq * rk * tempv;
        }
#pragma unroll
        for (int t = 0; t < 2; t++) {
            const int qrow = qb * 64 + wv * 32 + t * 16 + lr;
            short8 raw = *(const short8*)(qbase + (size_t)qrow * 192 + ks * 32 + koff);
            short8 sc;
#pragma unroll
            for (int j = 0; j < 8; j++)
                sc[j] = (short)f2bf(bf2f((u16)raw[j]) * scf[j]);
            qf[t][ks] = sc;
        }
    }

    float l_r[2][4];
    floatx4 oacc[2][12];
#pragma unroll
    for (int t = 0; t < 2; t++) {
#pragma unroll
        for (int r = 0; r < 4; r++) l_r[t][r] = 0.f;
#pragma unroll
        for (int vt = 0; vt < 12; vt++) oacc[t][vt] = (floatx4){0.f, 0.f, 0.f, 0.f};
    }

    u16* lp = lP + wv * 2048;

    for (int kb = 0; kb < 16; kb++) {
        __syncthreads();
        // stage 24 K chunks + 24 V chunks with 2 waves
#pragma unroll
        for (int i = 0; i < 12; i++) {
            int ch = i * 2 + wv;  // 0..23
            int ks = ch >> 2, nt = ch & 3;
            const u16* gk = kbase + ((size_t)(kb * 4 + nt) * 6 + ks) * 512 + lane * 8;
            gl_lds16(gk, (char*)lK + ch * 1024);
            int ks2 = ch / 12, vt2 = ch - ks2 * 12;
            const u16* gv = vbase + ((size_t)(kb * 2 + ks2) * 12 + vt2) * 512 + lane * 8;
            gl_lds16(gv, (char*)lV + ch * 1024);
        }
        __syncthreads();

        // S = Qs * K^T for both row-tiles; each kf read feeds 2 MFMAs
        floatx4 s0[4], s1[4];
#pragma unroll
        for (int nt = 0; nt < 4; nt++) {
            s0[nt] = (floatx4){0.f, 0.f, 0.f, 0.f};
            s1[nt] = (floatx4){0.f, 0.f, 0.f, 0.f};
        }
#pragma unroll
        for (int ks = 0; ks < 6; ks++) {
#pragma unroll
            for (int nt = 0; nt < 4; nt++) {
                short8 kf = *(const short8*)(lK + ((ks * 4 + nt) * 64 + lane) * 8);
                s0[nt] = __builtin_amdgcn_mfma_f32_16x16x32_bf16(qf[0][ks], kf, s0[nt], 0, 0, 0);
                s1[nt] = __builtin_amdgcn_mfma_f32_16x16x32_bf16(qf[1][ks], kf, s1[nt], 0, 0, 0);
            }
        }

        // exp (no max shift) + row-sum + P write (A-frag order), both tiles
        float rs0[4] = {0.f, 0.f, 0.f, 0.f}, rs1[4] = {0.f, 0.f, 0.f, 0.f};
#pragma unroll
        for (int nt = 0; nt < 4; nt++)
#pragma unroll
            for (int r = 0; r < 4; r++) {
                float p0 = __expf(s0[nt][r]);
                s0[nt][r] = p0;
                rs0[r] += p0;
                float p1 = __expf(s1[nt][r]);
                s1[nt][r] = p1;
                rs1[r] += p1;
            }
#pragma unroll
        for (int m = 1; m < 16; m <<= 1)
#pragma unroll
            for (int r = 0; r < 4; r++) {
                rs0[r] += __shfl_xor(rs0[r], m);
                rs1[r] += __shfl_xor(rs1[r], m);
            }
#pragma unroll
        for (int r = 0; r < 4; r++) {
            l_r[0][r] += rs0[r];
            l_r[1][r] += rs1[r];
        }
#pragma unroll
        for (int nt = 0; nt < 4; nt++) {
            int base2 = (nt >> 1) * 512 + ((nt & 1) * 2 + (lr >> 3)) * 128 + (lr & 7);
#pragma unroll
            for (int r = 0; r < 4; r++) {
                lp[base2 + (lq * 4 + r) * 8] = f2bf(s0[nt][r]);
                lp[1024 + base2 + (lq * 4 + r) * 8] = f2bf(s1[nt][r]);
            }
        }

        // O += P * V; each vf read feeds 2 MFMAs
#pragma unroll
        for (int ks2 = 0; ks2 < 2; ks2++) {
            short8 pf0 = *(const short8*)(lp + ks2 * 512 + lane * 8);
            short8 pf1 = *(const short8*)(lp + 1024 + ks2 * 512 + lane * 8);
#pragma unroll
            for (int vt = 0; vt < 12; vt++) {
                short8 vf = *(const short8*)(lV + ((ks2 * 12 + vt) * 64 + lane) * 8);
                oacc[0][vt] = __builtin_amdgcn_mfma_f32_16x16x32_bf16(pf0, vf, oacc[0][vt], 0, 0, 0);
                oacc[1][vt] = __builtin_amdgcn_mfma_f32_16x16x32_bf16(pf1, vf, oacc[1][vt], 0, 0, 0);
            }
        }
    }

    // epilogue: divide by l, write o in swiz (A-operand) layout for proj gemm
#pragma unroll
    for (int t = 0; t < 2; t++) {
        float inv[4];
#pragma unroll
        for (int r = 0; r < 4; r++) inv[r] = 1.f / l_r[t][r];
#pragma unroll
        for (int vt = 0; vt < 12; vt++) {
            int col = h * 192 + vt * 16 + lr;
#pragma unroll
            for (int r = 0; r < 4; r++) {
                int rowg = b * 1024 + qb * 64 + wv * 32 + t * 16 + lq * 4 + r;
                size_t addr = (size_t)(rowg >> 4) * 12288 + (col >> 5) * 512 +
                              ((col >> 3) & 3) * 128 + (rowg & 15) * 8 + (col & 7);
                o[addr] = f2bf(oacc[t][vt][r] * inv[r]);
            }
        }
    }
}

// ---------------- LN apply + transpose back + residual: y = LN(o2)^T + x ----------------
// (mu/rstd computed inline from musum/sqsum, removing the k_lnfin launch)
__global__ __launch_bounds__(256) void k_lnt(const float* __restrict__ o2,
                                             const float* __restrict__ musum,
                                             const float* __restrict__ sqsum,
                                             const float* __restrict__ gamma,
                                             const float* __restrict__ beta,
                                             const float* __restrict__ x,
                                             float* __restrict__ y) {
    __shared__ float tile[64][65];
    const int b = blockIdx.z, hw0 = blockIdx.y * 64, cd0 = blockIdx.x * 64;
    const int tid = threadIdx.x;
#pragma unroll
    for (int i = 0; i < 16; i++) {
        int f = i * 256 + tid;
        int hwl = f >> 6, cdl = f & 63;
        int row = b * 1024 + hw0 + hwl;
        float m_ = musum[row] * (1.f / 768.f);
        float var = fmaxf(sqsum[row] * (1.f / 768.f) - m_ * m_, 0.f);
        float rstd = rsqrtf(var + 1e-5f);
        float v = o2[(size_t)row * 768 + cd0 + cdl];
        v = (v - m_) * rstd * gamma[cd0 + cdl] + beta[cd0 + cdl];
        tile[hwl][cdl] = v;
    }
    __syncthreads();
#pragma unroll
    for (int i = 0; i < 16; i++) {
        int f = i * 256 + tid;
        int cdl = f >> 6, hwl = f & 63;
        int cd = cd0 + cdl, c = cd >> 3, d = cd & 7;
        size_t addr = (size_t)((b * 96 + c) * 8 + d) * 1024 + hw0 + hwl;
        y[addr] = tile[hwl][cdl] + x[addr];
    }
}

// ---------------- depthwise 3x3x3 conv: LDS-staged channel + rolling d-window ----------------
__global__ __launch_bounds__(256) void k_dw(const float* __restrict__ y,
                                            const float* __restrict__ w,
                                            const float* __restrict__ bias,
                                            float* __restrict__ z) {
    __shared__ float ly[8192];  // [d][h][w]
    const int bc = blockIdx.x;
    const int c = bc % 96;
    const int tid = threadIdx.x;
    const size_t base = (size_t)bc * 8192;

#pragma unroll
    for (int i = 0; i < 8; i++) {
        int i4 = i * 256 + tid;
        *(float4*)(ly + i4 * 4) = *(const float4*)(y + base + i4 * 4);
    }
    float wt[27];
#pragma unroll
    for (int j = 0; j < 27; j++) wt[j] = w[c * 27 + j];
    const float bv = bias[c];
    __syncthreads();

    const int wcol = tid & 31;
    const int hh = tid >> 5;  // 0..7

    for (int hb = 0; hb < 4; hb++) {
        const int h = hb * 8 + hh;
        float pl[3][9];
        auto loadplane = [&](int dd, float* p) {
#pragma unroll
            for (int kh = 0; kh < 3; kh++) {
                int h2 = h + kh - 1;
                bool hok = (unsigned)h2 < 32u;
                const float* row = ly + dd * 1024 + h2 * 32;
#pragma unroll
                for (int kw = 0; kw < 3; kw++) {
                    int w2 = wcol + kw - 1;
                    bool ok = hok && (unsigned)w2 < 32u;
                    p[kh * 3 + kw] = ok ? row[w2] : 0.f;
                }
            }
        };
#pragma unroll
        for (int j = 0; j < 9; j++) pl[0][j] = 0.f;  // d=-1 plane
        loadplane(0, pl[1]);
#pragma unroll
        for (int d = 0; d < 8; d++) {
            if (d < 7) loadplane(d + 1, pl[2]);
            else {
#pragma unroll
                for (int j = 0; j < 9; j++) pl[2][j] = 0.f;
            }
            float acc = bv;
#pragma unroll
            for (int kd = 0; kd < 3; kd++)
#pragma unroll
                for (int j = 0; j < 9; j++) acc += wt[kd * 9 + j] * pl[kd][j];
            z[base + d * 1024 + h * 32 + wcol] = acc;
#pragma unroll
            for (int j = 0; j < 9; j++) { pl[0][j] = pl[1][j]; pl[1][j] = pl[2][j]; }
        }
    }
}

// ---------------- pointwise conv via MFMA: out = y + pw_b + W(96x96) * Z(96 x pos) ----------------
__global__ __launch_bounds__(256) void k_pw(const float* __restrict__ z,
                                            const u16* __restrict__ wbf,   // bf16 96x96 row-major
                                            const float* __restrict__ bias,
                                            float* __restrict__ out) {
    __shared__ __align__(16) u16 lZ[128 * 104];
    __shared__ __align__(16) u16 lW[96 * 104];
    const int tid = threadIdx.x;
    const int lane = tid & 63;
    const int wv = tid >> 6;
    const int lr = lane & 15;
    const int lq = lane >> 4;
    const int koff = lq * 8;

    const int idx = blockIdx.x;
    const int q = idx & 7;
    const int bd = idx >> 3;
    const int b = bd >> 3, d = bd & 7;
    const int pos0 = q * 128;

    for (int i = tid; i < 96 * 96; i += 256) {
        int row = i / 96, col = i - row * 96;
        lW[row * 104 + col] = wbf[i];
    }
    {
        const int pos = tid & 127;
        const int cc0 = (tid >> 7) * 48;
        const size_t gbase = ((size_t)b * 96 * 8 + d) * 1024 + pos0 + pos;
#pragma unroll
        for (int g = 0; g < 6; g++) {
            short8 v;
#pragma unroll
            for (int j = 0; j < 8; j++) {
                int cc = cc0 + g * 8 + j;
                v[j] = (short)f2bf(z[gbase + (size_t)cc * 8192]);
            }
            *(short8*)(lZ + pos * 104 + cc0 + g * 8) = v;
        }
    }
    __syncthreads();

    floatx4 acc[6][2];
#pragma unroll
    for (int m = 0; m < 6; m++)
#pragma unroll
        for (int nt = 0; nt < 2; nt++) acc[m][nt] = (floatx4){0.f, 0.f, 0.f, 0.f};

#pragma unroll
    for (int ks = 0; ks < 3; ks++) {
        short8 bfrg[2];
#pragma unroll
        for (int nt = 0; nt < 2; nt++)
            bfrg[nt] = *(const short8*)(lZ + (wv * 32 + nt * 16 + lr) * 104 + ks * 32 + koff);
#pragma unroll
        for (int m = 0; m < 6; m++) {
            short8 afr = *(const short8*)(lW + (m * 16 + lr) * 104 + ks * 32 + koff);
#pragma unroll
            for (int nt = 0; nt < 2; nt++)
                acc[m][nt] = __builtin_amdgcn_mfma_f32_16x16x32_bf16(afr, bfrg[nt], acc[m][nt], 0, 0, 0);
        }
    }

#pragma unroll
    for (int m = 0; m < 6; m++) {
#pragma unroll
        for (int r = 0; r < 4; r++) {
            int c = m * 16 + lq * 4 + r;
            float bv = bias[c];
            size_t rowbase = ((size_t)(b * 96 + c) * 8 + d) * 1024 + pos0;
#pragma unroll
            for (int nt = 0; nt < 2; nt++) {
                int pos = wv * 32 + nt * 16 + lr;
                size_t a = rowbase + pos;
                out[a] = out[a] + bv + acc[m][nt][r];
            }
        }
    }
}

extern "C" void kernel_launch(void* const* d_in, const int* in_sizes, int n_in,
                              void* d_out, int out_size, void* d_ws, size_t ws_size,
                              hipStream_t stream) {
    (void)in_sizes; (void)n_in; (void)out_size; (void)ws_size;
    const float* x      = (const float*)d_in[0];
    const float* pos    = (const float*)d_in[1];
    const float* qkv_w  = (const float*)d_in[2];
    const float* proj_w = (const float*)d_in[3];
    const float* proj_b = (const float*)d_in[4];
    const float* temp   = (const float*)d_in[5];
    const float* ln_g   = (const float*)d_in[6];
    const float* ln_b   = (const float*)d_in[7];
    const float* dw_w   = (const float*)d_in[8];
    const float* dw_b   = (const float*)d_in[9];
    const float* pw_w   = (const float*)d_in[10];
    const float* pw_b   = (const float*)d_in[11];
    float* out = (float*)d_out;
    char* ws = (char*)d_ws;

    u16* t    = (u16*)(ws + 0);           // swiz A, 12.58MB ; later aliased by o (swiz) and z
    u16* vT   = (u16*)(ws + 12582912);    // v swiz, 12.58MB
    u16* q    = (u16*)(ws + 25165824);    // row-major, 12.58MB ; later o2 (with kk)
    u16* kk   = (u16*)(ws + 37748736);    // k swiz, 12.58MB
    u16* wqb  = (u16*)(ws + 50331648);    // qkv_w swiz + proj_w swiz + pw_w, ~4.74MB
    float* sqq   = (float*)(ws + 55175168);
    float* sqk   = (float*)(ws + 55199744);
    float* musum = (float*)(ws + 55224320);
    float* sqsum = (float*)(ws + 55257088);
    u16* wpb  = wqb + 2304 * 768;
    u16* wpwb = wqb + 2304 * 768 + 768 * 768;
    u16* o   = t;
    float* o2 = (float*)q;
    float* z  = (float*)t;
    float* y  = out;

    k_tpos<<<dim3(12, 16, 8), 256, 0, stream>>>(x, pos, t);
    k_cvt<<<1188, 256, 0, stream>>>(qkv_w, proj_w, pw_w, wqb);
    hipMemsetAsync(sqq, 0, 114688, stream);  // sqq + sqk + musum + sqsum
    gemm_bt<0><<<1152, 256, 0, stream>>>(t, wqb, 8192, 2304, 768, q, kk, vT, nullptr, nullptr,
                                         sqq, sqk, nullptr, nullptr);
    k_attn<<<512, 128, 0, stream>>>(q, kk, vT, sqq, sqk, temp, o);
    gemm_bt<1><<<384, 256, 0, stream>>>(o, wpb, 8192, 768, 768, nullptr, nullptr, nullptr, proj_b,
                                        o2, nullptr, nullptr, musum, sqsum);
    k_lnt<<<dim3(12, 16, 8), 256, 0, stream>>>(o2, musum, sqsum, ln_g, ln_b, x, y);
    k_dw<<<768, 256, 0, stream>>>(y, dw_w, dw_b, z);
    k_pw<<<512, 256, 0, stream>>>(z, wpwb, pw_b, out);
}

// Round 12
// 272.803 us; speedup vs baseline: 1.1330x; 1.0527x over previous
//
#include <hip/hip_runtime.h>

typedef unsigned short u16;
typedef unsigned int u32;

typedef __attribute__((ext_vector_type(8))) short short8;
typedef __attribute__((ext_vector_type(4))) float floatx4;

__device__ __forceinline__ float bf2f(u16 u) { return __uint_as_float(((u32)u) << 16); }
__device__ __forceinline__ u16 f2bf(float f) {
    u32 x = __float_as_uint(f);
    x += 0x7fffu + ((x >> 16) & 1u);
    return (u16)(x >> 16);
}
__device__ __forceinline__ void gl_lds16(const void* g, void* l) {
    __builtin_amdgcn_global_load_lds((const __attribute__((address_space(1))) u32*)g,
                                     (__attribute__((address_space(3))) u32*)l, 16, 0, 0);
}

// Fragment-tiled ("swiz") layouts: data grouped in 1024B chunks of [16 rows x 32 k],
// element order = gl_lds16 lane order: u16 off = chunk*512 + (((k>>3)&3)*16 + (row&15))*8 + (k&7).
// A-operands (t, o): chunk = (row>>4)*24 + (k>>5)   [K=768 -> 24 kchunks]
// W-operands (qkv_w, proj_w): same with row=n.
// K-swiz (per bh, n x dh): chunk = (n>>4)*6 + (dh>>5)
// V-swiz (per bh): chunk = (n>>5)*12 + (dh>>4), lane = ((n>>3)&3)*16 + (dh&15), low3 = n&7

// ---------------- fused startup: tpos-transpose | weight cvt | stats zeroing ----------------
// blocks [0,1536): x -> t swiz bf16 + pos ; [1536,2724): weight cvt ; [2724,2836): zero stats
__global__ __launch_bounds__(256) void k_init(const float* __restrict__ x,
                                              const float* __restrict__ pos,
                                              const float* __restrict__ wq,
                                              const float* __restrict__ wp,
                                              const float* __restrict__ wpw,
                                              u16* __restrict__ t,
                                              u16* __restrict__ wout,
                                              float* __restrict__ zbuf) {
    __shared__ float tile[64][65];
    const int bid = blockIdx.x;
    const int tid = threadIdx.x;
    if (bid < 1536) {
        const int cd0 = (bid % 12) * 64;
        const int hw0 = ((bid / 12) & 15) * 64;
        const int b = bid / 192;
#pragma unroll
        for (int i = 0; i < 16; i++) {
            int f = i * 256 + tid;
            int cdl = f >> 6, hwl = f & 63;
            int cd = cd0 + cdl, c = cd >> 3, d = cd & 7;
            tile[cdl][hwl] = x[(size_t)(((b * 96 + c) * 8 + d)) * 1024 + hw0 + hwl];
        }
        __syncthreads();
#pragma unroll
        for (int it = 0; it < 2; it++) {
            int u = it * 256 + tid;       // 512 units of 16B
            int ch = u >> 6, l = u & 63;
            int n16l = ch >> 1, kcl = ch & 1;
            int hwl = n16l * 16 + (l & 15);
            int cdl = kcl * 32 + (l >> 4) * 8;
            int row = b * 1024 + hw0 + hwl;
            int cd = cd0 + cdl;
            const float* pp = pos + (size_t)(hw0 + hwl) * 768 + cd;
            float4 p0 = *(const float4*)pp;
            float4 p1 = *(const float4*)(pp + 4);
            short8 v;
            v[0] = (short)f2bf(tile[cdl + 0][hwl] + p0.x);
            v[1] = (short)f2bf(tile[cdl + 1][hwl] + p0.y);
            v[2] = (short)f2bf(tile[cdl + 2][hwl] + p0.z);
            v[3] = (short)f2bf(tile[cdl + 3][hwl] + p0.w);
            v[4] = (short)f2bf(tile[cdl + 4][hwl] + p1.x);
            v[5] = (short)f2bf(tile[cdl + 5][hwl] + p1.y);
            v[6] = (short)f2bf(tile[cdl + 6][hwl] + p1.z);
            v[7] = (short)f2bf(tile[cdl + 7][hwl] + p1.w);
            size_t chunk = (size_t)(row >> 4) * 24 + (cd >> 5);
            *(short8*)(t + chunk * 512 + l * 8) = v;
        }
    } else if (bid < 2724) {
        const int NQ = 144 * 24 * 64;          // qkv 16B-units
        const int NP = NQ + 48 * 24 * 64;      // + proj 16B-units
        int u = (bid - 1536) * 256 + tid;
        if (u < NP) {
            const float* w = (u < NQ) ? wq : wp;
            int ub = (u < NQ) ? u : u - NQ;
            int chunk = ub >> 6, l = ub & 63;
            int n16 = chunk / 24, kc = chunk - n16 * 24;
            int n = n16 * 16 + (l & 15);
            int k0 = kc * 32 + (l >> 4) * 8;
            const float* src = w + (size_t)n * 768 + k0;
            float4 a = *(const float4*)src;
            float4 b2 = *(const float4*)(src + 4);
            short8 v;
            v[0] = (short)f2bf(a.x);  v[1] = (short)f2bf(a.y);
            v[2] = (short)f2bf(a.z);  v[3] = (short)f2bf(a.w);
            v[4] = (short)f2bf(b2.x); v[5] = (short)f2bf(b2.y);
            v[6] = (short)f2bf(b2.z); v[7] = (short)f2bf(b2.w);
            *(short8*)(wout + (size_t)u * 8) = v;
        } else {
            int i = u - NP;  // 9216 pw elements
            wout[(size_t)NP * 8 + i] = f2bf(wpw[i]);
        }
    } else {
        int i = (bid - 2724) * 256 + tid;  // 28672 floats: sqq|sqk|musum|sqsum
        zbuf[i] = 0.f;
    }
}

// ---------------- GEMM: C(M,N) = A_swiz(M,K) * W_swiz(N,K)^T, bf16 MFMA ----------------
// BK=64, XCD-pinned swizzle. MODE 0 k/v epilogue staged through LDS -> 1024B coalesced stores.
// Fused stats: MODE 0 accumulates column sum-of-squares (q,k) into sqa/ska;
// MODE 1 accumulates row sum / sum-of-squares into musum/sqsum.
template <int MODE>
__global__ __launch_bounds__(256) void gemm_bt(const u16* __restrict__ A,
                                               const u16* __restrict__ Bw,
                                               int M, int N, int K,
                                               u16* __restrict__ qo, u16* __restrict__ ko,
                                               u16* __restrict__ vo,
                                               const float* __restrict__ bias,
                                               float* __restrict__ Co,
                                               float* __restrict__ sqa,
                                               float* __restrict__ ska,
                                               float* __restrict__ musum,
                                               float* __restrict__ sqsum) {
    __shared__ __align__(16) u16 lAB[32 * 512];  // 32KB: lA = [0..16), lB = [16..32) chunks
    u16* lA = lAB;
    u16* lB = lAB + 16 * 512;
    const int tid = threadIdx.x;
    const int lane = tid & 63;
    const int wv = tid >> 6;
    const int wr = wv >> 1, wc = wv & 1;
    const int ntiles = N >> 7;
    const int mtiles = M >> 7;                 // 64
    const int lin = blockIdx.x;
    const int xcd = lin & 7;
    const int idx = lin >> 3;
    const int mlocal = idx / ntiles;
    const int ntile = idx - mlocal * ntiles;
    const int m0 = (xcd * (mtiles >> 3) + mlocal) << 7;
    const int n0 = ntile << 7;
    const int lr = lane & 15;
    const int lq = lane >> 4;

    floatx4 acc[4][4];
#pragma unroll
    for (int i = 0; i < 4; i++)
#pragma unroll
        for (int j = 0; j < 4; j++) acc[i][j] = (floatx4){0.f, 0.f, 0.f, 0.f};

    const int m16 = m0 >> 4, n16 = n0 >> 4;
    for (int kc2 = 0; kc2 < (K >> 6); kc2++) {
        __syncthreads();
#pragma unroll
        for (int kh = 0; kh < 2; kh++) {
#pragma unroll
            for (int i = 0; i < 2; i++) {
                int ch16 = i * 4 + wv;       // 16-row block of the 128-row tile
                int kc = kc2 * 2 + kh;
                const u16* ga = A + ((size_t)(m16 + ch16) * 24 + kc) * 512 + lane * 8;
                gl_lds16(ga, (char*)lA + (kh * 8 + ch16) * 1024);
                const u16* gb = Bw + ((size_t)(n16 + ch16) * 24 + kc) * 512 + lane * 8;
                gl_lds16(gb, (char*)lB + (kh * 8 + ch16) * 1024);
            }
        }
        __syncthreads();
#pragma unroll
        for (int kh = 0; kh < 2; kh++) {
            short8 af[4], bfr[4];
#pragma unroll
            for (int tt = 0; tt < 4; tt++) {
                af[tt] = *(const short8*)(lA + ((kh * 8 + wr * 4 + tt) * 64 + lane) * 8);
                bfr[tt] = *(const short8*)(lB + ((kh * 8 + wc * 4 + tt) * 64 + lane) * 8);
            }
#pragma unroll
            for (int mt = 0; mt < 4; mt++)
#pragma unroll
                for (int nt = 0; nt < 4; nt++)
                    acc[mt][nt] = __builtin_amdgcn_mfma_f32_16x16x32_bf16(af[mt], bfr[nt], acc[mt][nt], 0, 0, 0);
        }
    }

    if (MODE == 0) {
        const int region = n0 / 768;       // whole block is q, k, or v
        const int n0r = n0 - region * 768;
        const int bb0 = m0 >> 10;
        // fused column sum-of-squares for q (region 0) and k (region 1)
        if (region < 2) {
            float* dst = (region == 0) ? sqa : ska;
#pragma unroll
            for (int nt = 0; nt < 4; nt++) {
                int colb = n0r + wc * 64 + nt * 16;
                int h = colb / 192;
                int dh = colb - h * 192 + lr;
                float s = 0.f;
#pragma unroll
                for (int mt = 0; mt < 4; mt++)
#pragma unroll
                    for (int r = 0; r < 4; r++) s += acc[mt][nt][r] * acc[mt][nt][r];
                s += __shfl_xor(s, 16);
                s += __shfl_xor(s, 32);
                if (lq == 0) atomicAdd(&dst[(bb0 * 4 + h) * 192 + dh], s);
            }
        }
        if (region == 0) {
            // q: direct row-major stores (32B segments)
#pragma unroll
            for (int nt = 0; nt < 4; nt++) {
                int colb = n0r + wc * 64 + nt * 16;
                int h = colb / 192;
                int dh = colb - h * 192 + lr;
#pragma unroll
                for (int mt = 0; mt < 4; mt++) {
#pragma unroll
                    for (int r = 0; r < 4; r++) {
                        int row = m0 + wr * 64 + mt * 16 + lq * 4 + r;
                        int b = row >> 10, n = row & 1023;
                        qo[((size_t)(b * 4 + h) * 1024 + n) * 192 + dh] = f2bf(acc[mt][nt][r]);
                    }
                }
            }
        } else {
            // k/v: stage the 128x128 bf16 tile in LDS at swiz-exact offsets, bulk-copy out
            __syncthreads();
            if (region == 1) {
#pragma unroll
                for (int nt = 0; nt < 4; nt++) {
                    int lch = wc * 2 + (nt >> 1);
                    int offbase = (((nt & 1) * 2 + (lr >> 3)) * 16) * 8 + (lr & 7);
#pragma unroll
                    for (int mt = 0; mt < 4; mt++) {
                        u16* cp2 = lAB + (((wr * 4 + mt) * 4 + lch) * 512);
#pragma unroll
                        for (int r = 0; r < 4; r++)
                            cp2[offbase + (lq * 4 + r) * 8] = f2bf(acc[mt][nt][r]);
                    }
                }
            } else {
#pragma unroll
                for (int nt = 0; nt < 4; nt++) {
#pragma unroll
                    for (int mt = 0; mt < 4; mt++) {
                        u16* cp2 = lAB + (((wr * 2 + (mt >> 1)) * 8 + wc * 4 + nt) * 512);
                        int ob = (((mt & 1) * 2 + (lq >> 1)) * 16 + lr) * 8 + (lq & 1) * 4;
#pragma unroll
                        for (int r = 0; r < 4; r++)
                            cp2[ob + r] = f2bf(acc[mt][nt][r]);
                    }
                }
            }
            __syncthreads();
            const int b = m0 >> 10;
            const int ml = m0 & 1023;
#pragma unroll
            for (int i = 0; i < 8; i++) {
                int ci = wv * 8 + i;
                short8 val = *(const short8*)(lAB + ci * 512 + lane * 8);
                if (region == 1) {
                    int a = ci >> 2, bb = ci & 3;
                    int cg = n0r + bb * 32;
                    int h = cg / 192;
                    int dh32 = (cg - h * 192) >> 5;
                    size_t gaddr = (size_t)(b * 4 + h) * 196608 +
                                   (size_t)((((ml >> 4) + a) * 6 + dh32)) * 512 + lane * 8;
                    *(short8*)(ko + gaddr) = val;
                } else {
                    int a = ci >> 3, bb = ci & 7;
                    int cg = n0r + bb * 16;
                    int h = cg / 192;
                    int dh16 = (cg - h * 192) >> 4;
                    size_t gaddr = (size_t)(b * 4 + h) * 196608 +
                                   (size_t)((((ml >> 5) + a) * 12 + dh16)) * 512 + lane * 8;
                    *(short8*)(vo + gaddr) = val;
                }
            }
        }
    } else {
        float bvv[4];
#pragma unroll
        for (int nt = 0; nt < 4; nt++) bvv[nt] = bias[n0 + wc * 64 + nt * 16 + lr];
#pragma unroll
        for (int nt = 0; nt < 4; nt++) {
            int col = n0 + wc * 64 + nt * 16 + lr;
#pragma unroll
            for (int mt = 0; mt < 4; mt++) {
#pragma unroll
                for (int r = 0; r < 4; r++) {
                    int row = m0 + wr * 64 + mt * 16 + lq * 4 + r;
                    Co[(size_t)row * N + col] = acc[mt][nt][r] + bvv[nt];
                }
            }
        }
        // fused LN row stats: sum and sum-of-squares over this block's 128 cols
#pragma unroll
        for (int mt = 0; mt < 4; mt++) {
#pragma unroll
            for (int r = 0; r < 4; r++) {
                float s = 0.f, ss = 0.f;
#pragma unroll
                for (int nt = 0; nt < 4; nt++) {
                    float v = acc[mt][nt][r] + bvv[nt];
                    s += v;
                    ss += v * v;
                }
#pragma unroll
                for (int m = 1; m < 16; m <<= 1) {
                    s += __shfl_xor(s, m);
                    ss += __shfl_xor(ss, m);
                }
                if (lr == 0) {
                    int row = m0 + wr * 64 + mt * 16 + lq * 4 + r;
                    atomicAdd(&musum[row], s);
                    atomicAdd(&sqsum[row], ss);
                }
            }
        }
    }
}

__global__ void k_scale(const float* __restrict__ sqq, const float* __restrict__ sqk,
                        const float* __restrict__ temp, float* __restrict__ cs) {
    int bh = blockIdx.x;
    int dh = threadIdx.x;
    float rq = 1.f / fmaxf(sqrtf(sqq[bh * 192 + dh]), 1e-12f);
    float rk = 1.f / fmaxf(sqrtf(sqk[bh * 192 + dh]), 1e-12f);
    cs[bh * 192 + dh] = rq * rk * temp[bh & 3];
}

// ---------------- flash attention: 2-wave blocks, 32 q-rows/wave (2 tiles), no-max softmax ----
__global__ __launch_bounds__(128) void k_attn(const u16* __restrict__ q,
                                              const u16* __restrict__ kmat,
                                              const u16* __restrict__ vT,
                                              const float* __restrict__ cs,
                                              u16* __restrict__ o) {
    __shared__ __align__(16) u16 lK[24 * 512];
    __shared__ __align__(16) u16 lV[24 * 512];
    __shared__ __align__(16) u16 lP[2 * 2048];  // per-wave 2 P-tiles
    const int lin = blockIdx.x;
    const int qb = (lin >> 3) & 15;
    const int bh = (lin & 7) * 4 + (lin >> 7);
    const int b = bh >> 2, h = bh & 3;
    const int tid = threadIdx.x;
    const int lane = tid & 63;
    const int wv = tid >> 6;   // 0..1
    const int lr = lane & 15;
    const int lq = lane >> 4;
    const int koff = lq * 8;

    const u16* qbase = q + (size_t)bh * 1024 * 192;
    const u16* kbase = kmat + (size_t)bh * 196608;
    const u16* vbase = vT + (size_t)bh * 196608;
    const float* cp = cs + bh * 192;

    // Q fragments for the wave's 2 row-tiles, pre-scaled
    short8 qf[2][6];
#pragma unroll
    for (int t = 0; t < 2; t++) {
        const int qrow = qb * 64 + wv * 32 + t * 16 + lr;
        const u16* qp = qbase + (size_t)qrow * 192;
#pragma unroll
        for (int ks = 0; ks < 6; ks++) {
            short8 raw = *(const short8*)(qp + ks * 32 + koff);
            short8 sc;
#pragma unroll
            for (int j = 0; j < 8; j++) {
                float f = bf2f((u16)raw[j]) * cp[ks * 32 + koff + j];
                sc[j] = (short)f2bf(f);
            }
            qf[t][ks] = sc;
        }
    }

    float l_r[2][4];
    floatx4 oacc[2][12];
#pragma unroll
    for (int t = 0; t < 2; t++) {
#pragma unroll
        for (int r = 0; r < 4; r++) l_r[t][r] = 0.f;
#pragma unroll
        for (int vt = 0; vt < 12; vt++) oacc[t][vt] = (floatx4){0.f, 0.f, 0.f, 0.f};
    }

    u16* lp = lP + wv * 2048;

    for (int kb = 0; kb < 16; kb++) {
        __syncthreads();
        // stage 24 K chunks + 24 V chunks with 2 waves
#pragma unroll
        for (int i = 0; i < 12; i++) {
            int ch = i * 2 + wv;  // 0..23
            int ks = ch >> 2, nt = ch & 3;
            const u16* gk = kbase + ((size_t)(kb * 4 + nt) * 6 + ks) * 512 + lane * 8;
            gl_lds16(gk, (char*)lK + ch * 1024);
            int ks2 = ch / 12, vt2 = ch - ks2 * 12;
            const u16* gv = vbase + ((size_t)(kb * 2 + ks2) * 12 + vt2) * 512 + lane * 8;
            gl_lds16(gv, (char*)lV + ch * 1024);
        }
        __syncthreads();

        // S = Qs * K^T for both row-tiles; each kf read feeds 2 MFMAs
        floatx4 s0[4], s1[4];
#pragma unroll
        for (int nt = 0; nt < 4; nt++) {
            s0[nt] = (floatx4){0.f, 0.f, 0.f, 0.f};
            s1[nt] = (floatx4){0.f, 0.f, 0.f, 0.f};
        }
#pragma unroll
        for (int ks = 0; ks < 6; ks++) {
#pragma unroll
            for (int nt = 0; nt < 4; nt++) {
                short8 kf = *(const short8*)(lK + ((ks * 4 + nt) * 64 + lane) * 8);
                s0[nt] = __builtin_amdgcn_mfma_f32_16x16x32_bf16(qf[0][ks], kf, s0[nt], 0, 0, 0);
                s1[nt] = __builtin_amdgcn_mfma_f32_16x16x32_bf16(qf[1][ks], kf, s1[nt], 0, 0, 0);
            }
        }

        // exp (no max shift) + row-sum + P write (A-frag order), both tiles
        float rs0[4] = {0.f, 0.f, 0.f, 0.f}, rs1[4] = {0.f, 0.f, 0.f, 0.f};
#pragma unroll
        for (int nt = 0; nt < 4; nt++)
#pragma unroll
            for (int r = 0; r < 4; r++) {
                float p0 = __expf(s0[nt][r]);
                s0[nt][r] = p0;
                rs0[r] += p0;
                float p1 = __expf(s1[nt][r]);
                s1[nt][r] = p1;
                rs1[r] += p1;
            }
#pragma unroll
        for (int m = 1; m < 16; m <<= 1)
#pragma unroll
            for (int r = 0; r < 4; r++) {
                rs0[r] += __shfl_xor(rs0[r], m);
                rs1[r] += __shfl_xor(rs1[r], m);
            }
#pragma unroll
        for (int r = 0; r < 4; r++) {
            l_r[0][r] += rs0[r];
            l_r[1][r] += rs1[r];
        }
#pragma unroll
        for (int nt = 0; nt < 4; nt++) {
            int base2 = (nt >> 1) * 512 + ((nt & 1) * 2 + (lr >> 3)) * 128 + (lr & 7);
#pragma unroll
            for (int r = 0; r < 4; r++) {
                lp[base2 + (lq * 4 + r) * 8] = f2bf(s0[nt][r]);
                lp[1024 + base2 + (lq * 4 + r) * 8] = f2bf(s1[nt][r]);
            }
        }

        // O += P * V; each vf read feeds 2 MFMAs
#pragma unroll
        for (int ks2 = 0; ks2 < 2; ks2++) {
            short8 pf0 = *(const short8*)(lp + ks2 * 512 + lane * 8);
            short8 pf1 = *(const short8*)(lp + 1024 + ks2 * 512 + lane * 8);
#pragma unroll
            for (int vt = 0; vt < 12; vt++) {
                short8 vf = *(const short8*)(lV + ((ks2 * 12 + vt) * 64 + lane) * 8);
                oacc[0][vt] = __builtin_amdgcn_mfma_f32_16x16x32_bf16(pf0, vf, oacc[0][vt], 0, 0, 0);
                oacc[1][vt] = __builtin_amdgcn_mfma_f32_16x16x32_bf16(pf1, vf, oacc[1][vt], 0, 0, 0);
            }
        }
    }

    // epilogue: divide by l, write o in swiz (A-operand) layout for proj gemm
#pragma unroll
    for (int t = 0; t < 2; t++) {
        float inv[4];
#pragma unroll
        for (int r = 0; r < 4; r++) inv[r] = 1.f / l_r[t][r];
#pragma unroll
        for (int vt = 0; vt < 12; vt++) {
            int col = h * 192 + vt * 16 + lr;
#pragma unroll
            for (int r = 0; r < 4; r++) {
                int rowg = b * 1024 + qb * 64 + wv * 32 + t * 16 + lq * 4 + r;
                size_t addr = (size_t)(rowg >> 4) * 12288 + (col >> 5) * 512 +
                              ((col >> 3) & 3) * 128 + (rowg & 15) * 8 + (col & 7);
                o[addr] = f2bf(oacc[t][vt][r] * inv[r]);
            }
        }
    }
}

// ---------------- LN apply + transpose back + residual: y = LN(o2)^T + x ----------------
// (mu/rstd computed inline from musum/sqsum)
__global__ __launch_bounds__(256) void k_lnt(const float* __restrict__ o2,
                                             const float* __restrict__ musum,
                                             const float* __restrict__ sqsum,
                                             const float* __restrict__ gamma,
                                             const float* __restrict__ beta,
                                             const float* __restrict__ x,
                                             float* __restrict__ y) {
    __shared__ float tile[64][65];
    const int b = blockIdx.z, hw0 = blockIdx.y * 64, cd0 = blockIdx.x * 64;
    const int tid = threadIdx.x;
#pragma unroll
    for (int i = 0; i < 16; i++) {
        int f = i * 256 + tid;
        int hwl = f >> 6, cdl = f & 63;
        int row = b * 1024 + hw0 + hwl;
        float m_ = musum[row] * (1.f / 768.f);
        float var = fmaxf(sqsum[row] * (1.f / 768.f) - m_ * m_, 0.f);
        float rstd = rsqrtf(var + 1e-5f);
        float v = o2[(size_t)row * 768 + cd0 + cdl];
        v = (v - m_) * rstd * gamma[cd0 + cdl] + beta[cd0 + cdl];
        tile[hwl][cdl] = v;
    }
    __syncthreads();
#pragma unroll
    for (int i = 0; i < 16; i++) {
        int f = i * 256 + tid;
        int cdl = f >> 6, hwl = f & 63;
        int cd = cd0 + cdl, c = cd >> 3, d = cd & 7;
        size_t addr = (size_t)((b * 96 + c) * 8 + d) * 1024 + hw0 + hwl;
        y[addr] = tile[hwl][cdl] + x[addr];
    }
}

// ---------------- depthwise 3x3x3 conv: LDS-staged channel + rolling d-window ----------------
__global__ __launch_bounds__(256) void k_dw(const float* __restrict__ y,
                                            const float* __restrict__ w,
                                            const float* __restrict__ bias,
                                            float* __restrict__ z) {
    __shared__ float ly[8192];  // [d][h][w]
    const int bc = blockIdx.x;
    const int c = bc % 96;
    const int tid = threadIdx.x;
    const size_t base = (size_t)bc * 8192;

#pragma unroll
    for (int i = 0; i < 8; i++) {
        int i4 = i * 256 + tid;
        *(float4*)(ly + i4 * 4) = *(const float4*)(y + base + i4 * 4);
    }
    float wt[27];
#pragma unroll
    for (int j = 0; j < 27; j++) wt[j] = w[c * 27 + j];
    const float bv = bias[c];
    __syncthreads();

    const int wcol = tid & 31;
    const int hh = tid >> 5;  // 0..7

    for (int hb = 0; hb < 4; hb++) {
        const int h = hb * 8 + hh;
        float pl[3][9];
        auto loadplane = [&](int dd, float* p) {
#pragma unroll
            for (int kh = 0; kh < 3; kh++) {
                int h2 = h + kh - 1;
                bool hok = (unsigned)h2 < 32u;
                const float* row = ly + dd * 1024 + h2 * 32;
#pragma unroll
                for (int kw = 0; kw < 3; kw++) {
                    int w2 = wcol + kw - 1;
                    bool ok = hok && (unsigned)w2 < 32u;
                    p[kh * 3 + kw] = ok ? row[w2] : 0.f;
                }
            }
        };
#pragma unroll
        for (int j = 0; j < 9; j++) pl[0][j] = 0.f;  // d=-1 plane
        loadplane(0, pl[1]);
#pragma unroll
        for (int d = 0; d < 8; d++) {
            if (d < 7) loadplane(d + 1, pl[2]);
            else {
#pragma unroll
                for (int j = 0; j < 9; j++) pl[2][j] = 0.f;
            }
            float acc = bv;
#pragma unroll
            for (int kd = 0; kd < 3; kd++)
#pragma unroll
                for (int j = 0; j < 9; j++) acc += wt[kd * 9 + j] * pl[kd][j];
            z[base + d * 1024 + h * 32 + wcol] = acc;
#pragma unroll
            for (int j = 0; j < 9; j++) { pl[0][j] = pl[1][j]; pl[1][j] = pl[2][j]; }
        }
    }
}

// ---------------- pointwise conv via MFMA: out = y + pw_b + W(96x96) * Z(96 x pos) ----------------
__global__ __launch_bounds__(256) void k_pw(const float* __restrict__ z,
                                            const u16* __restrict__ wbf,   // bf16 96x96 row-major
                                            const float* __restrict__ bias,
                                            float* __restrict__ out) {
    __shared__ __align__(16) u16 lZ[128 * 104];
    __shared__ __align__(16) u16 lW[96 * 104];
    const int tid = threadIdx.x;
    const int lane = tid & 63;
    const int wv = tid >> 6;
    const int lr = lane & 15;
    const int lq = lane >> 4;
    const int koff = lq * 8;

    const int idx = blockIdx.x;
    const int q = idx & 7;
    const int bd = idx >> 3;
    const int b = bd >> 3, d = bd & 7;
    const int pos0 = q * 128;

    for (int i = tid; i < 96 * 96; i += 256) {
        int row = i / 96, col = i - row * 96;
        lW[row * 104 + col] = wbf[i];
    }
    {
        const int pos = tid & 127;
        const int cc0 = (tid >> 7) * 48;
        const size_t gbase = ((size_t)b * 96 * 8 + d) * 1024 + pos0 + pos;
#pragma unroll
        for (int g = 0; g < 6; g++) {
            short8 v;
#pragma unroll
            for (int j = 0; j < 8; j++) {
                int cc = cc0 + g * 8 + j;
                v[j] = (short)f2bf(z[gbase + (size_t)cc * 8192]);
            }
            *(short8*)(lZ + pos * 104 + cc0 + g * 8) = v;
        }
    }
    __syncthreads();

    floatx4 acc[6][2];
#pragma unroll
    for (int m = 0; m < 6; m++)
#pragma unroll
        for (int nt = 0; nt < 2; nt++) acc[m][nt] = (floatx4){0.f, 0.f, 0.f, 0.f};

#pragma unroll
    for (int ks = 0; ks < 3; ks++) {
        short8 bfrg[2];
#pragma unroll
        for (int nt = 0; nt < 2; nt++)
            bfrg[nt] = *(const short8*)(lZ + (wv * 32 + nt * 16 + lr) * 104 + ks * 32 + koff);
#pragma unroll
        for (int m = 0; m < 6; m++) {
            short8 afr = *(const short8*)(lW + (m * 16 + lr) * 104 + ks * 32 + koff);
#pragma unroll
            for (int nt = 0; nt < 2; nt++)
                acc[m][nt] = __builtin_amdgcn_mfma_f32_16x16x32_bf16(afr, bfrg[nt], acc[m][nt], 0, 0, 0);
        }
    }

#pragma unroll
    for (int m = 0; m < 6; m++) {
#pragma unroll
        for (int r = 0; r < 4; r++) {
            int c = m * 16 + lq * 4 + r;
            float bv = bias[c];
            size_t rowbase = ((size_t)(b * 96 + c) * 8 + d) * 1024 + pos0;
#pragma unroll
            for (int nt = 0; nt < 2; nt++) {
                int pos = wv * 32 + nt * 16 + lr;
                size_t a = rowbase + pos;
                out[a] = out[a] + bv + acc[m][nt][r];
            }
        }
    }
}

extern "C" void kernel_launch(void* const* d_in, const int* in_sizes, int n_in,
                              void* d_out, int out_size, void* d_ws, size_t ws_size,
                              hipStream_t stream) {
    (void)in_sizes; (void)n_in; (void)out_size; (void)ws_size;
    const float* x      = (const float*)d_in[0];
    const float* pos    = (const float*)d_in[1];
    const float* qkv_w  = (const float*)d_in[2];
    const float* proj_w = (const float*)d_in[3];
    const float* proj_b = (const float*)d_in[4];
    const float* temp   = (const float*)d_in[5];
    const float* ln_g   = (const float*)d_in[6];
    const float* ln_b   = (const float*)d_in[7];
    const float* dw_w   = (const float*)d_in[8];
    const float* dw_b   = (const float*)d_in[9];
    const float* pw_w   = (const float*)d_in[10];
    const float* pw_b   = (const float*)d_in[11];
    float* out = (float*)d_out;
    char* ws = (char*)d_ws;

    u16* t    = (u16*)(ws + 0);           // swiz A, 12.58MB ; later aliased by o (swiz) and z
    u16* vT   = (u16*)(ws + 12582912);    // v swiz, 12.58MB
    u16* q    = (u16*)(ws + 25165824);    // row-major, 12.58MB ; later o2 (with kk)
    u16* kk   = (u16*)(ws + 37748736);    // k swiz, 12.58MB
    u16* wqb  = (u16*)(ws + 50331648);    // qkv_w swiz + proj_w swiz + pw_w, ~4.74MB
    float* cs    = (float*)(ws + 55150592);
    float* sqq   = (float*)(ws + 55175168);  // sqq|sqk|musum|sqsum contiguous, 114688B
    float* sqk   = (float*)(ws + 55199744);
    float* musum = (float*)(ws + 55224320);
    float* sqsum = (float*)(ws + 55257088);
    u16* wpb  = wqb + 2304 * 768;
    u16* wpwb = wqb + 2304 * 768 + 768 * 768;
    u16* o   = t;
    float* o2 = (float*)q;
    float* z  = (float*)t;
    float* y  = out;

    k_init<<<2836, 256, 0, stream>>>(x, pos, qkv_w, proj_w, pw_w, t, wqb, sqq);
    gemm_bt<0><<<1152, 256, 0, stream>>>(t, wqb, 8192, 2304, 768, q, kk, vT, nullptr, nullptr,
                                         sqq, sqk, nullptr, nullptr);
    k_scale<<<32, 192, 0, stream>>>(sqq, sqk, temp, cs);
    k_attn<<<512, 128, 0, stream>>>(q, kk, vT, cs, o);
    gemm_bt<1><<<384, 256, 0, stream>>>(o, wpb, 8192, 768, 768, nullptr, nullptr, nullptr, proj_b,
                                        o2, nullptr, nullptr, musum, sqsum);
    k_lnt<<<dim3(12, 16, 8), 256, 0, stream>>>(o2, musum, sqsum, ln_g, ln_b, x, y);
    k_dw<<<768, 256, 0, stream>>>(y, dw_w, dw_b, z);
    k_pw<<<512, 256, 0, stream>>>(z, wpwb, pw_b, out);
}

// Round 13
// 271.748 us; speedup vs baseline: 1.1374x; 1.0039x over previous
//
#include <hip/hip_runtime.h>

typedef unsigned short u16;
typedef unsigned int u32;

typedef __attribute__((ext_vector_type(8))) short short8;
typedef __attribute__((ext_vector_type(4))) float floatx4;

__device__ __forceinline__ float bf2f(u16 u) { return __uint_as_float(((u32)u) << 16); }
__device__ __forceinline__ u16 f2bf(float f) {
    u32 x = __float_as_uint(f);
    x += 0x7fffu + ((x >> 16) & 1u);
    return (u16)(x >> 16);
}
__device__ __forceinline__ void gl_lds16(const void* g, void* l) {
    __builtin_amdgcn_global_load_lds((const __attribute__((address_space(1))) u32*)g,
                                     (__attribute__((address_space(3))) u32*)l, 16, 0, 0);
}

// Fragment-tiled ("swiz") layouts: data grouped in 1024B chunks of [16 rows x 32 k],
// element order = gl_lds16 lane order: u16 off = chunk*512 + (((k>>3)&3)*16 + (row&15))*8 + (k&7).
// A-operands (t, o): chunk = (row>>4)*24 + (k>>5)   [K=768 -> 24 kchunks]
// W-operands (qkv_w, proj_w): same with row=n.
// K-swiz (per bh, n x dh): chunk = (n>>4)*6 + (dh>>5)
// V-swiz (per bh): chunk = (n>>5)*12 + (dh>>4), lane = ((n>>3)&3)*16 + (dh&15), low3 = n&7

// ---------------- fused startup: tpos-transpose | weight cvt | stats zeroing ----------------
// blocks [0,1536): x -> t swiz bf16 + pos ; [1536,2724): weight cvt ; [2724,2836): zero stats
__global__ __launch_bounds__(256) void k_init(const float* __restrict__ x,
                                              const float* __restrict__ pos,
                                              const float* __restrict__ wq,
                                              const float* __restrict__ wp,
                                              const float* __restrict__ wpw,
                                              u16* __restrict__ t,
                                              u16* __restrict__ wout,
                                              float* __restrict__ zbuf) {
    __shared__ float tile[64][65];
    const int bid = blockIdx.x;
    const int tid = threadIdx.x;
    if (bid < 1536) {
        const int cd0 = (bid % 12) * 64;
        const int hw0 = ((bid / 12) & 15) * 64;
        const int b = bid / 192;
#pragma unroll
        for (int i = 0; i < 16; i++) {
            int f = i * 256 + tid;
            int cdl = f >> 6, hwl = f & 63;
            int cd = cd0 + cdl, c = cd >> 3, d = cd & 7;
            tile[cdl][hwl] = x[(size_t)(((b * 96 + c) * 8 + d)) * 1024 + hw0 + hwl];
        }
        __syncthreads();
#pragma unroll
        for (int it = 0; it < 2; it++) {
            int u = it * 256 + tid;       // 512 units of 16B
            int ch = u >> 6, l = u & 63;
            int n16l = ch >> 1, kcl = ch & 1;
            int hwl = n16l * 16 + (l & 15);
            int cdl = kcl * 32 + (l >> 4) * 8;
            int row = b * 1024 + hw0 + hwl;
            int cd = cd0 + cdl;
            const float* pp = pos + (size_t)(hw0 + hwl) * 768 + cd;
            float4 p0 = *(const float4*)pp;
            float4 p1 = *(const float4*)(pp + 4);
            short8 v;
            v[0] = (short)f2bf(tile[cdl + 0][hwl] + p0.x);
            v[1] = (short)f2bf(tile[cdl + 1][hwl] + p0.y);
            v[2] = (short)f2bf(tile[cdl + 2][hwl] + p0.z);
            v[3] = (short)f2bf(tile[cdl + 3][hwl] + p0.w);
            v[4] = (short)f2bf(tile[cdl + 4][hwl] + p1.x);
            v[5] = (short)f2bf(tile[cdl + 5][hwl] + p1.y);
            v[6] = (short)f2bf(tile[cdl + 6][hwl] + p1.z);
            v[7] = (short)f2bf(tile[cdl + 7][hwl] + p1.w);
            size_t chunk = (size_t)(row >> 4) * 24 + (cd >> 5);
            *(short8*)(t + chunk * 512 + l * 8) = v;
        }
    } else if (bid < 2724) {
        const int NQ = 144 * 24 * 64;          // qkv 16B-units
        const int NP = NQ + 48 * 24 * 64;      // + proj 16B-units
        int u = (bid - 1536) * 256 + tid;
        if (u < NP) {
            const float* w = (u < NQ) ? wq : wp;
            int ub = (u < NQ) ? u : u - NQ;
            int chunk = ub >> 6, l = ub & 63;
            int n16 = chunk / 24, kc = chunk - n16 * 24;
            int n = n16 * 16 + (l & 15);
            int k0 = kc * 32 + (l >> 4) * 8;
            const float* src = w + (size_t)n * 768 + k0;
            float4 a = *(const float4*)src;
            float4 b2 = *(const float4*)(src + 4);
            short8 v;
            v[0] = (short)f2bf(a.x);  v[1] = (short)f2bf(a.y);
            v[2] = (short)f2bf(a.z);  v[3] = (short)f2bf(a.w);
            v[4] = (short)f2bf(b2.x); v[5] = (short)f2bf(b2.y);
            v[6] = (short)f2bf(b2.z); v[7] = (short)f2bf(b2.w);
            *(short8*)(wout + (size_t)u * 8) = v;
        } else {
            int i = u - NP;  // 9216 pw elements
            wout[(size_t)NP * 8 + i] = f2bf(wpw[i]);
        }
    } else {
        int i = (bid - 2724) * 256 + tid;  // 28672 floats: sqq|sqk|musum|sqsum
        zbuf[i] = 0.f;
    }
}

// ---------------- GEMM: C(M,N) = A_swiz(M,K) * W_swiz(N,K)^T, bf16 MFMA ----------------
// BK=64, XCD-pinned swizzle. MODE 0 k/v epilogue staged through LDS -> 1024B coalesced stores.
// Fused stats: MODE 0 accumulates column sum-of-squares (q,k) into sqa/ska;
// MODE 1 accumulates row sum / sum-of-squares into musum/sqsum; writes Co in bf16.
template <int MODE>
__global__ __launch_bounds__(256) void gemm_bt(const u16* __restrict__ A,
                                               const u16* __restrict__ Bw,
                                               int M, int N, int K,
                                               u16* __restrict__ qo, u16* __restrict__ ko,
                                               u16* __restrict__ vo,
                                               const float* __restrict__ bias,
                                               u16* __restrict__ Co,
                                               float* __restrict__ sqa,
                                               float* __restrict__ ska,
                                               float* __restrict__ musum,
                                               float* __restrict__ sqsum) {
    __shared__ __align__(16) u16 lAB[32 * 512];  // 32KB: lA = [0..16), lB = [16..32) chunks
    u16* lA = lAB;
    u16* lB = lAB + 16 * 512;
    const int tid = threadIdx.x;
    const int lane = tid & 63;
    const int wv = tid >> 6;
    const int wr = wv >> 1, wc = wv & 1;
    const int ntiles = N >> 7;
    const int mtiles = M >> 7;                 // 64
    const int lin = blockIdx.x;
    const int xcd = lin & 7;
    const int idx = lin >> 3;
    const int mlocal = idx / ntiles;
    const int ntile = idx - mlocal * ntiles;
    const int m0 = (xcd * (mtiles >> 3) + mlocal) << 7;
    const int n0 = ntile << 7;
    const int lr = lane & 15;
    const int lq = lane >> 4;

    floatx4 acc[4][4];
#pragma unroll
    for (int i = 0; i < 4; i++)
#pragma unroll
        for (int j = 0; j < 4; j++) acc[i][j] = (floatx4){0.f, 0.f, 0.f, 0.f};

    const int m16 = m0 >> 4, n16 = n0 >> 4;
    for (int kc2 = 0; kc2 < (K >> 6); kc2++) {
        __syncthreads();
#pragma unroll
        for (int kh = 0; kh < 2; kh++) {
#pragma unroll
            for (int i = 0; i < 2; i++) {
                int ch16 = i * 4 + wv;       // 16-row block of the 128-row tile
                int kc = kc2 * 2 + kh;
                const u16* ga = A + ((size_t)(m16 + ch16) * 24 + kc) * 512 + lane * 8;
                gl_lds16(ga, (char*)lA + (kh * 8 + ch16) * 1024);
                const u16* gb = Bw + ((size_t)(n16 + ch16) * 24 + kc) * 512 + lane * 8;
                gl_lds16(gb, (char*)lB + (kh * 8 + ch16) * 1024);
            }
        }
        __syncthreads();
#pragma unroll
        for (int kh = 0; kh < 2; kh++) {
            short8 af[4], bfr[4];
#pragma unroll
            for (int tt = 0; tt < 4; tt++) {
                af[tt] = *(const short8*)(lA + ((kh * 8 + wr * 4 + tt) * 64 + lane) * 8);
                bfr[tt] = *(const short8*)(lB + ((kh * 8 + wc * 4 + tt) * 64 + lane) * 8);
            }
#pragma unroll
            for (int mt = 0; mt < 4; mt++)
#pragma unroll
                for (int nt = 0; nt < 4; nt++)
                    acc[mt][nt] = __builtin_amdgcn_mfma_f32_16x16x32_bf16(af[mt], bfr[nt], acc[mt][nt], 0, 0, 0);
        }
    }

    if (MODE == 0) {
        const int region = n0 / 768;       // whole block is q, k, or v
        const int n0r = n0 - region * 768;
        const int bb0 = m0 >> 10;
        // fused column sum-of-squares for q (region 0) and k (region 1)
        if (region < 2) {
            float* dst = (region == 0) ? sqa : ska;
#pragma unroll
            for (int nt = 0; nt < 4; nt++) {
                int colb = n0r + wc * 64 + nt * 16;
                int h = colb / 192;
                int dh = colb - h * 192 + lr;
                float s = 0.f;
#pragma unroll
                for (int mt = 0; mt < 4; mt++)
#pragma unroll
                    for (int r = 0; r < 4; r++) s += acc[mt][nt][r] * acc[mt][nt][r];
                s += __shfl_xor(s, 16);
                s += __shfl_xor(s, 32);
                if (lq == 0) atomicAdd(&dst[(bb0 * 4 + h) * 192 + dh], s);
            }
        }
        if (region == 0) {
            // q: direct row-major stores (32B segments)
#pragma unroll
            for (int nt = 0; nt < 4; nt++) {
                int colb = n0r + wc * 64 + nt * 16;
                int h = colb / 192;
                int dh = colb - h * 192 + lr;
#pragma unroll
                for (int mt = 0; mt < 4; mt++) {
#pragma unroll
                    for (int r = 0; r < 4; r++) {
                        int row = m0 + wr * 64 + mt * 16 + lq * 4 + r;
                        int b = row >> 10, n = row & 1023;
                        qo[((size_t)(b * 4 + h) * 1024 + n) * 192 + dh] = f2bf(acc[mt][nt][r]);
                    }
                }
            }
        } else {
            // k/v: stage the 128x128 bf16 tile in LDS at swiz-exact offsets, bulk-copy out
            __syncthreads();
            if (region == 1) {
#pragma unroll
                for (int nt = 0; nt < 4; nt++) {
                    int lch = wc * 2 + (nt >> 1);
                    int offbase = (((nt & 1) * 2 + (lr >> 3)) * 16) * 8 + (lr & 7);
#pragma unroll
                    for (int mt = 0; mt < 4; mt++) {
                        u16* cp2 = lAB + (((wr * 4 + mt) * 4 + lch) * 512);
#pragma unroll
                        for (int r = 0; r < 4; r++)
                            cp2[offbase + (lq * 4 + r) * 8] = f2bf(acc[mt][nt][r]);
                    }
                }
            } else {
#pragma unroll
                for (int nt = 0; nt < 4; nt++) {
#pragma unroll
                    for (int mt = 0; mt < 4; mt++) {
                        u16* cp2 = lAB + (((wr * 2 + (mt >> 1)) * 8 + wc * 4 + nt) * 512);
                        int ob = (((mt & 1) * 2 + (lq >> 1)) * 16 + lr) * 8 + (lq & 1) * 4;
#pragma unroll
                        for (int r = 0; r < 4; r++)
                            cp2[ob + r] = f2bf(acc[mt][nt][r]);
                    }
                }
            }
            __syncthreads();
            const int b = m0 >> 10;
            const int ml = m0 & 1023;
#pragma unroll
            for (int i = 0; i < 8; i++) {
                int ci = wv * 8 + i;
                short8 val = *(const short8*)(lAB + ci * 512 + lane * 8);
                if (region == 1) {
                    int a = ci >> 2, bb = ci & 3;
                    int cg = n0r + bb * 32;
                    int h = cg / 192;
                    int dh32 = (cg - h * 192) >> 5;
                    size_t gaddr = (size_t)(b * 4 + h) * 196608 +
                                   (size_t)((((ml >> 4) + a) * 6 + dh32)) * 512 + lane * 8;
                    *(short8*)(ko + gaddr) = val;
                } else {
                    int a = ci >> 3, bb = ci & 7;
                    int cg = n0r + bb * 16;
                    int h = cg / 192;
                    int dh16 = (cg - h * 192) >> 4;
                    size_t gaddr = (size_t)(b * 4 + h) * 196608 +
                                   (size_t)((((ml >> 5) + a) * 12 + dh16)) * 512 + lane * 8;
                    *(short8*)(vo + gaddr) = val;
                }
            }
        }
    } else {
        float bvv[4];
#pragma unroll
        for (int nt = 0; nt < 4; nt++) bvv[nt] = bias[n0 + wc * 64 + nt * 16 + lr];
#pragma unroll
        for (int nt = 0; nt < 4; nt++) {
            int col = n0 + wc * 64 + nt * 16 + lr;
#pragma unroll
            for (int mt = 0; mt < 4; mt++) {
#pragma unroll
                for (int r = 0; r < 4; r++) {
                    int row = m0 + wr * 64 + mt * 16 + lq * 4 + r;
                    Co[(size_t)row * N + col] = f2bf(acc[mt][nt][r] + bvv[nt]);
                }
            }
        }
        // fused LN row stats: sum and sum-of-squares over this block's 128 cols
#pragma unroll
        for (int mt = 0; mt < 4; mt++) {
#pragma unroll
            for (int r = 0; r < 4; r++) {
                float s = 0.f, ss = 0.f;
#pragma unroll
                for (int nt = 0; nt < 4; nt++) {
                    float v = acc[mt][nt][r] + bvv[nt];
                    s += v;
                    ss += v * v;
                }
#pragma unroll
                for (int m = 1; m < 16; m <<= 1) {
                    s += __shfl_xor(s, m);
                    ss += __shfl_xor(ss, m);
                }
                if (lr == 0) {
                    int row = m0 + wr * 64 + mt * 16 + lq * 4 + r;
                    atomicAdd(&musum[row], s);
                    atomicAdd(&sqsum[row], ss);
                }
            }
        }
    }
}

__global__ void k_scale(const float* __restrict__ sqq, const float* __restrict__ sqk,
                        const float* __restrict__ temp, float* __restrict__ cs) {
    int bh = blockIdx.x;
    int dh = threadIdx.x;
    float rq = 1.f / fmaxf(sqrtf(sqq[bh * 192 + dh]), 1e-12f);
    float rk = 1.f / fmaxf(sqrtf(sqk[bh * 192 + dh]), 1e-12f);
    cs[bh * 192 + dh] = rq * rk * temp[bh & 3];
}

// ---------------- flash attention: 2-wave blocks, 32 q-rows/wave (2 tiles), no-max softmax ----
__global__ __launch_bounds__(128) void k_attn(const u16* __restrict__ q,
                                              const u16* __restrict__ kmat,
                                              const u16* __restrict__ vT,
                                              const float* __restrict__ cs,
                                              u16* __restrict__ o) {
    __shared__ __align__(16) u16 lK[24 * 512];
    __shared__ __align__(16) u16 lV[24 * 512];
    __shared__ __align__(16) u16 lP[2 * 2048];  // per-wave 2 P-tiles
    const int lin = blockIdx.x;
    const int qb = (lin >> 3) & 15;
    const int bh = (lin & 7) * 4 + (lin >> 7);
    const int b = bh >> 2, h = bh & 3;
    const int tid = threadIdx.x;
    const int lane = tid & 63;
    const int wv = tid >> 6;   // 0..1
    const int lr = lane & 15;
    const int lq = lane >> 4;
    const int koff = lq * 8;

    const u16* qbase = q + (size_t)bh * 1024 * 192;
    const u16* kbase = kmat + (size_t)bh * 196608;
    const u16* vbase = vT + (size_t)bh * 196608;
    const float* cp = cs + bh * 192;

    // Q fragments for the wave's 2 row-tiles, pre-scaled
    short8 qf[2][6];
#pragma unroll
    for (int t = 0; t < 2; t++) {
        const int qrow = qb * 64 + wv * 32 + t * 16 + lr;
        const u16* qp = qbase + (size_t)qrow * 192;
#pragma unroll
        for (int ks = 0; ks < 6; ks++) {
            short8 raw = *(const short8*)(qp + ks * 32 + koff);
            short8 sc;
#pragma unroll
            for (int j = 0; j < 8; j++) {
                float f = bf2f((u16)raw[j]) * cp[ks * 32 + koff + j];
                sc[j] = (short)f2bf(f);
            }
            qf[t][ks] = sc;
        }
    }

    float l_r[2][4];
    floatx4 oacc[2][12];
#pragma unroll
    for (int t = 0; t < 2; t++) {
#pragma unroll
        for (int r = 0; r < 4; r++) l_r[t][r] = 0.f;
#pragma unroll
        for (int vt = 0; vt < 12; vt++) oacc[t][vt] = (floatx4){0.f, 0.f, 0.f, 0.f};
    }

    u16* lp = lP + wv * 2048;

    for (int kb = 0; kb < 16; kb++) {
        __syncthreads();
        // stage 24 K chunks + 24 V chunks with 2 waves
#pragma unroll
        for (int i = 0; i < 12; i++) {
            int ch = i * 2 + wv;  // 0..23
            int ks = ch >> 2, nt = ch & 3;
            const u16* gk = kbase + ((size_t)(kb * 4 + nt) * 6 + ks) * 512 + lane * 8;
            gl_lds16(gk, (char*)lK + ch * 1024);
            int ks2 = ch / 12, vt2 = ch - ks2 * 12;
            const u16* gv = vbase + ((size_t)(kb * 2 + ks2) * 12 + vt2) * 512 + lane * 8;
            gl_lds16(gv, (char*)lV + ch * 1024);
        }
        __syncthreads();

        // S = Qs * K^T for both row-tiles; each kf read feeds 2 MFMAs
        floatx4 s0[4], s1[4];
#pragma unroll
        for (int nt = 0; nt < 4; nt++) {
            s0[nt] = (floatx4){0.f, 0.f, 0.f, 0.f};
            s1[nt] = (floatx4){0.f, 0.f, 0.f, 0.f};
        }
#pragma unroll
        for (int ks = 0; ks < 6; ks++) {
#pragma unroll
            for (int nt = 0; nt < 4; nt++) {
                short8 kf = *(const short8*)(lK + ((ks * 4 + nt) * 64 + lane) * 8);
                s0[nt] = __builtin_amdgcn_mfma_f32_16x16x32_bf16(qf[0][ks], kf, s0[nt], 0, 0, 0);
                s1[nt] = __builtin_amdgcn_mfma_f32_16x16x32_bf16(qf[1][ks], kf, s1[nt], 0, 0, 0);
            }
        }

        // exp (no max shift) + row-sum + P write (A-frag order), both tiles
        float rs0[4] = {0.f, 0.f, 0.f, 0.f}, rs1[4] = {0.f, 0.f, 0.f, 0.f};
#pragma unroll
        for (int nt = 0; nt < 4; nt++)
#pragma unroll
            for (int r = 0; r < 4; r++) {
                float p0 = __expf(s0[nt][r]);
                s0[nt][r] = p0;
                rs0[r] += p0;
                float p1 = __expf(s1[nt][r]);
                s1[nt][r] = p1;
                rs1[r] += p1;
            }
#pragma unroll
        for (int m = 1; m < 16; m <<= 1)
#pragma unroll
            for (int r = 0; r < 4; r++) {
                rs0[r] += __shfl_xor(rs0[r], m);
                rs1[r] += __shfl_xor(rs1[r], m);
            }
#pragma unroll
        for (int r = 0; r < 4; r++) {
            l_r[0][r] += rs0[r];
            l_r[1][r] += rs1[r];
        }
#pragma unroll
        for (int nt = 0; nt < 4; nt++) {
            int base2 = (nt >> 1) * 512 + ((nt & 1) * 2 + (lr >> 3)) * 128 + (lr & 7);
#pragma unroll
            for (int r = 0; r < 4; r++) {
                lp[base2 + (lq * 4 + r) * 8] = f2bf(s0[nt][r]);
                lp[1024 + base2 + (lq * 4 + r) * 8] = f2bf(s1[nt][r]);
            }
        }

        // O += P * V; each vf read feeds 2 MFMAs
#pragma unroll
        for (int ks2 = 0; ks2 < 2; ks2++) {
            short8 pf0 = *(const short8*)(lp + ks2 * 512 + lane * 8);
            short8 pf1 = *(const short8*)(lp + 1024 + ks2 * 512 + lane * 8);
#pragma unroll
            for (int vt = 0; vt < 12; vt++) {
                short8 vf = *(const short8*)(lV + ((ks2 * 12 + vt) * 64 + lane) * 8);
                oacc[0][vt] = __builtin_amdgcn_mfma_f32_16x16x32_bf16(pf0, vf, oacc[0][vt], 0, 0, 0);
                oacc[1][vt] = __builtin_amdgcn_mfma_f32_16x16x32_bf16(pf1, vf, oacc[1][vt], 0, 0, 0);
            }
        }
    }

    // epilogue: divide by l, write o in swiz (A-operand) layout for proj gemm
#pragma unroll
    for (int t = 0; t < 2; t++) {
        float inv[4];
#pragma unroll
        for (int r = 0; r < 4; r++) inv[r] = 1.f / l_r[t][r];
#pragma unroll
        for (int vt = 0; vt < 12; vt++) {
            int col = h * 192 + vt * 16 + lr;
#pragma unroll
            for (int r = 0; r < 4; r++) {
                int rowg = b * 1024 + qb * 64 + wv * 32 + t * 16 + lq * 4 + r;
                size_t addr = (size_t)(rowg >> 4) * 12288 + (col >> 5) * 512 +
                              ((col >> 3) & 3) * 128 + (rowg & 15) * 8 + (col & 7);
                o[addr] = f2bf(oacc[t][vt][r] * inv[r]);
            }
        }
    }
}

// ---------------- LN apply + transpose back + residual: y = LN(o2)^T + x ----------------
// (mu/rstd computed inline from musum/sqsum; o2 is bf16)
__global__ __launch_bounds__(256) void k_lnt(const u16* __restrict__ o2,
                                             const float* __restrict__ musum,
                                             const float* __restrict__ sqsum,
                                             const float* __restrict__ gamma,
                                             const float* __restrict__ beta,
                                             const float* __restrict__ x,
                                             float* __restrict__ y) {
    __shared__ float tile[64][65];
    const int b = blockIdx.z, hw0 = blockIdx.y * 64, cd0 = blockIdx.x * 64;
    const int tid = threadIdx.x;
#pragma unroll
    for (int i = 0; i < 16; i++) {
        int f = i * 256 + tid;
        int hwl = f >> 6, cdl = f & 63;
        int row = b * 1024 + hw0 + hwl;
        float m_ = musum[row] * (1.f / 768.f);
        float var = fmaxf(sqsum[row] * (1.f / 768.f) - m_ * m_, 0.f);
        float rstd = rsqrtf(var + 1e-5f);
        float v = bf2f(o2[(size_t)row * 768 + cd0 + cdl]);
        v = (v - m_) * rstd * gamma[cd0 + cdl] + beta[cd0 + cdl];
        tile[hwl][cdl] = v;
    }
    __syncthreads();
#pragma unroll
    for (int i = 0; i < 16; i++) {
        int f = i * 256 + tid;
        int cdl = f >> 6, hwl = f & 63;
        int cd = cd0 + cdl, c = cd >> 3, d = cd & 7;
        size_t addr = (size_t)((b * 96 + c) * 8 + d) * 1024 + hw0 + hwl;
        y[addr] = tile[hwl][cdl] + x[addr];
    }
}

// ---------------- depthwise 3x3x3 conv: LDS-staged channel + rolling d-window ----------------
// z written in bf16 (halves z traffic; feeds pw conv whose contribution is small)
__global__ __launch_bounds__(256) void k_dw(const float* __restrict__ y,
                                            const float* __restrict__ w,
                                            const float* __restrict__ bias,
                                            u16* __restrict__ z) {
    __shared__ float ly[8192];  // [d][h][w]
    const int bc = blockIdx.x;
    const int c = bc % 96;
    const int tid = threadIdx.x;
    const size_t base = (size_t)bc * 8192;

#pragma unroll
    for (int i = 0; i < 8; i++) {
        int i4 = i * 256 + tid;
        *(float4*)(ly + i4 * 4) = *(const float4*)(y + base + i4 * 4);
    }
    float wt[27];
#pragma unroll
    for (int j = 0; j < 27; j++) wt[j] = w[c * 27 + j];
    const float bv = bias[c];
    __syncthreads();

    const int wcol = tid & 31;
    const int hh = tid >> 5;  // 0..7

    for (int hb = 0; hb < 4; hb++) {
        const int h = hb * 8 + hh;
        float pl[3][9];
        auto loadplane = [&](int dd, float* p) {
#pragma unroll
            for (int kh = 0; kh < 3; kh++) {
                int h2 = h + kh - 1;
                bool hok = (unsigned)h2 < 32u;
                const float* row = ly + dd * 1024 + h2 * 32;
#pragma unroll
                for (int kw = 0; kw < 3; kw++) {
                    int w2 = wcol + kw - 1;
                    bool ok = hok && (unsigned)w2 < 32u;
                    p[kh * 3 + kw] = ok ? row[w2] : 0.f;
                }
            }
        };
#pragma unroll
        for (int j = 0; j < 9; j++) pl[0][j] = 0.f;  // d=-1 plane
        loadplane(0, pl[1]);
#pragma unroll
        for (int d = 0; d < 8; d++) {
            if (d < 7) loadplane(d + 1, pl[2]);
            else {
#pragma unroll
                for (int j = 0; j < 9; j++) pl[2][j] = 0.f;
            }
            float acc = bv;
#pragma unroll
            for (int kd = 0; kd < 3; kd++)
#pragma unroll
                for (int j = 0; j < 9; j++) acc += wt[kd * 9 + j] * pl[kd][j];
            z[base + d * 1024 + h * 32 + wcol] = f2bf(acc);
#pragma unroll
            for (int j = 0; j < 9; j++) { pl[0][j] = pl[1][j]; pl[1][j] = pl[2][j]; }
        }
    }
}

// ---------------- pointwise conv via MFMA: out = y + pw_b + W(96x96) * Z(96 x pos) ----------------
// z is already bf16: staging is a straight u16 copy
__global__ __launch_bounds__(256) void k_pw(const u16* __restrict__ z,
                                            const u16* __restrict__ wbf,   // bf16 96x96 row-major
                                            const float* __restrict__ bias,
                                            float* __restrict__ out) {
    __shared__ __align__(16) u16 lZ[128 * 104];
    __shared__ __align__(16) u16 lW[96 * 104];
    const int tid = threadIdx.x;
    const int lane = tid & 63;
    const int wv = tid >> 6;
    const int lr = lane & 15;
    const int lq = lane >> 4;
    const int koff = lq * 8;

    const int idx = blockIdx.x;
    const int q = idx & 7;
    const int bd = idx >> 3;
    const int b = bd >> 3, d = bd & 7;
    const int pos0 = q * 128;

    for (int i = tid; i < 96 * 96; i += 256) {
        int row = i / 96, col = i - row * 96;
        lW[row * 104 + col] = wbf[i];
    }
    {
        const int pos = tid & 127;
        const int cc0 = (tid >> 7) * 48;
        const size_t gbase = ((size_t)b * 96 * 8 + d) * 1024 + pos0 + pos;
#pragma unroll
        for (int g = 0; g < 6; g++) {
            short8 v;
#pragma unroll
            for (int j = 0; j < 8; j++) {
                int cc = cc0 + g * 8 + j;
                v[j] = (short)z[gbase + (size_t)cc * 8192];
            }
            *(short8*)(lZ + pos * 104 + cc0 + g * 8) = v;
        }
    }
    __syncthreads();

    floatx4 acc[6][2];
#pragma unroll
    for (int m = 0; m < 6; m++)
#pragma unroll
        for (int nt = 0; nt < 2; nt++) acc[m][nt] = (floatx4){0.f, 0.f, 0.f, 0.f};

#pragma unroll
    for (int ks = 0; ks < 3; ks++) {
        short8 bfrg[2];
#pragma unroll
        for (int nt = 0; nt < 2; nt++)
            bfrg[nt] = *(const short8*)(lZ + (wv * 32 + nt * 16 + lr) * 104 + ks * 32 + koff);
#pragma unroll
        for (int m = 0; m < 6; m++) {
            short8 afr = *(const short8*)(lW + (m * 16 + lr) * 104 + ks * 32 + koff);
#pragma unroll
            for (int nt = 0; nt < 2; nt++)
                acc[m][nt] = __builtin_amdgcn_mfma_f32_16x16x32_bf16(afr, bfrg[nt], acc[m][nt], 0, 0, 0);
        }
    }

#pragma unroll
    for (int m = 0; m < 6; m++) {
#pragma unroll
        for (int r = 0; r < 4; r++) {
            int c = m * 16 + lq * 4 + r;
            float bv = bias[c];
            size_t rowbase = ((size_t)(b * 96 + c) * 8 + d) * 1024 + pos0;
#pragma unroll
            for (int nt = 0; nt < 2; nt++) {
                int pos = wv * 32 + nt * 16 + lr;
                size_t a = rowbase + pos;
                out[a] = out[a] + bv + acc[m][nt][r];
            }
        }
    }
}

extern "C" void kernel_launch(void* const* d_in, const int* in_sizes, int n_in,
                              void* d_out, int out_size, void* d_ws, size_t ws_size,
                              hipStream_t stream) {
    (void)in_sizes; (void)n_in; (void)out_size; (void)ws_size;
    const float* x      = (const float*)d_in[0];
    const float* pos    = (const float*)d_in[1];
    const float* qkv_w  = (const float*)d_in[2];
    const float* proj_w = (const float*)d_in[3];
    const float* proj_b = (const float*)d_in[4];
    const float* temp   = (const float*)d_in[5];
    const float* ln_g   = (const float*)d_in[6];
    const float* ln_b   = (const float*)d_in[7];
    const float* dw_w   = (const float*)d_in[8];
    const float* dw_b   = (const float*)d_in[9];
    const float* pw_w   = (const float*)d_in[10];
    const float* pw_b   = (const float*)d_in[11];
    float* out = (float*)d_out;
    char* ws = (char*)d_ws;

    u16* t    = (u16*)(ws + 0);           // swiz A, 12.58MB ; later aliased by o (swiz) and z
    u16* vT   = (u16*)(ws + 12582912);    // v swiz, 12.58MB
    u16* q    = (u16*)(ws + 25165824);    // row-major, 12.58MB ; later o2 bf16 (aliases q)
    u16* kk   = (u16*)(ws + 37748736);    // k swiz, 12.58MB
    u16* wqb  = (u16*)(ws + 50331648);    // qkv_w swiz + proj_w swiz + pw_w, ~4.74MB
    float* cs    = (float*)(ws + 55150592);
    float* sqq   = (float*)(ws + 55175168);  // sqq|sqk|musum|sqsum contiguous, 114688B
    float* sqk   = (float*)(ws + 55199744);
    float* musum = (float*)(ws + 55224320);
    float* sqsum = (float*)(ws + 55257088);
    u16* wpb  = wqb + 2304 * 768;
    u16* wpwb = wqb + 2304 * 768 + 768 * 768;
    u16* o   = t;
    u16* o2  = q;       // proj output bf16, aliases q (dead after attention)
    u16* z   = t;       // depthwise output bf16, aliases t (dead after proj GEMM)
    float* y  = out;

    k_init<<<2836, 256, 0, stream>>>(x, pos, qkv_w, proj_w, pw_w, t, wqb, sqq);
    gemm_bt<0><<<1152, 256, 0, stream>>>(t, wqb, 8192, 2304, 768, q, kk, vT, nullptr, nullptr,
                                         sqq, sqk, nullptr, nullptr);
    k_scale<<<32, 192, 0, stream>>>(sqq, sqk, temp, cs);
    k_attn<<<512, 128, 0, stream>>>(q, kk, vT, cs, o);
    gemm_bt<1><<<384, 256, 0, stream>>>(o, wpb, 8192, 768, 768, nullptr, nullptr, nullptr, proj_b,
                                        o2, nullptr, nullptr, musum, sqsum);
    k_lnt<<<dim3(12, 16, 8), 256, 0, stream>>>(o2, musum, sqsum, ln_g, ln_b, x, y);
    k_dw<<<768, 256, 0, stream>>>(y, dw_w, dw_b, z);
    k_pw<<<512, 256, 0, stream>>>(z, wpwb, pw_b, out);
}